// Round 1
// baseline (83229.633 us; speedup 1.0000x reference)
//
#include <hip/hip_runtime.h>
#include <math.h>

#define NBLK 256
#define NTHR 512

constexpr int Bb   = 32;    // batch
constexpr int Tt   = 256;   // timesteps
constexpr int FEAT = 640;
constexpr int Hh   = 2048;  // hidden
constexpr int Pp   = 640;   // projection
constexpr int G4H  = 8192;  // 4*H
constexpr int HB   = 8;     // hidden units per block (2048/256)

__device__ __forceinline__ float sigm(float v) { return 1.0f / (1.0f + expf(-v)); }

// Grid-wide barrier: monotone counter, agent-scope fences.
// Requires all NBLK blocks co-resident (cooperative launch).
__device__ __forceinline__ void grid_bar(unsigned int* bar, unsigned int& epoch) {
    __syncthreads();
    epoch++;
    if (threadIdx.x == 0) {
        __threadfence();                       // release: drain our stores device-wide
        atomicAdd(bar, 1u);
        const unsigned int target = epoch * NBLK;
        while (__hip_atomic_load(bar, __ATOMIC_RELAXED, __HIP_MEMORY_SCOPE_AGENT) < target) {
            __builtin_amdgcn_s_sleep(1);
        }
        __threadfence();                       // acquire: invalidate stale caches
    }
    __syncthreads();
}

__global__ void __launch_bounds__(NTHR, 1) lstm_persist(
    const float* __restrict__ x,
    const float* __restrict__ W0, const float* __restrict__ b0, const float* __restrict__ Pr0,
    const float* __restrict__ W1, const float* __restrict__ b1, const float* __restrict__ Pr1,
    float* out,        // [B,T,P]; layer0 stores its output here, layer1 reads+overwrites
    float* ws)
{
    const int tid = threadIdx.x;
    const int bid = blockIdx.x;

    unsigned int* bar = (unsigned int*)ws;     // zeroed by hipMemsetAsync each call
    float* mbuf0 = ws + 64;                    // [B][P]
    float* mbuf1 = mbuf0 + Bb * Pp;            // [B][P]
    float* hws   = mbuf1 + Bb * Pp;            // [H][B]

    __shared__ float zbuf[32 * 33];            // gate exchange, padded
    __shared__ float pred[512];                // proj K-split partials

    unsigned int epoch = 0;

    // ---- gate-phase mapping: 32 columns (4 gates x 8 hidden) x 16 batch-pairs ----
    const int c_idx = tid & 31;                // column within block
    const int bg    = tid >> 5;                // 0..15 batch-pair group
    const int b0r   = bg * 2;                  // first batch row of this thread
    const int col   = (c_idx >> 3) * Hh + bid * HB + (c_idx & 7);  // global gate column

    // ---- c-update mapping (threads 0..255): one (hidden, batch) cell each ----
    const int ch = tid >> 5;                   // local hidden 0..7 (valid tid<256)
    const int cb = tid & 31;                   // batch 0..31

    // ---- projection mapping: this block owns p in [p_s, p_e) ----
    const int p_s  = (bid * Pp) / NBLK;
    const int p_e  = ((bid + 1) * Pp) / NBLK;
    const int np   = p_e - p_s;                // 2 or 3
    const int kq_n = (np == 2) ? 8 : 4;        // K-split factor
    const int klen = Hh / kq_n;                // 256 or 512
    const int pg   = tid >> 5;                 // 0..15
    const bool pact = pg < np * kq_n;          // active thread-group?
    const int pj   = pact ? (pg % np) : 0;     // which p column
    const int kq   = pact ? (pg / np) : 0;     // which K chunk

    for (int layer = 0; layer < 2; ++layer) {
        const float* W   = layer ? W1  : W0;
        const float* bbv = layer ? b1  : b0;
        const float* Pr  = layer ? Pr1 : Pr0;
        const float* inb = layer ? (const float*)out : x;   // layer1 input = layer0 output

        // zero m0 (initial recurrent state)
        for (int i = bid * NTHR + tid; i < Bb * Pp; i += NBLK * NTHR) mbuf0[i] = 0.0f;
        float creg = 0.0f;                     // this thread's c cell (tid<256)
        grid_bar(bar, epoch);

        const float bias = bbv[col];

        for (int t = 0; t < Tt; ++t) {
            float* mcur = (t & 1) ? mbuf1 : mbuf0;
            float* mnxt = (t & 1) ? mbuf0 : mbuf1;

            // ================= gate phase: z = [x_t, m] @ W + b =================
            const float* in0 = inb + (size_t)(b0r * Tt + t) * 640;
            const float* in1 = in0 + (size_t)Tt * 640;
            const float* wp  = W + col;
            float a0 = 0.f, a1 = 0.f;
            #pragma unroll 4
            for (int k = 0; k < 640; k += 4) {
                float4 u0 = *(const float4*)(in0 + k);
                float4 u1 = *(const float4*)(in1 + k);
                float w0 = wp[(size_t)(k + 0) * G4H];
                float w1 = wp[(size_t)(k + 1) * G4H];
                float w2 = wp[(size_t)(k + 2) * G4H];
                float w3 = wp[(size_t)(k + 3) * G4H];
                a0 += w0 * u0.x + w1 * u0.y + w2 * u0.z + w3 * u0.w;
                a1 += w0 * u1.x + w1 * u1.y + w2 * u1.z + w3 * u1.w;
            }
            const float* q0 = mcur + (size_t)b0r * Pp;
            const float* q1 = q0 + Pp;
            #pragma unroll 4
            for (int k = 0; k < 640; k += 4) {
                float4 u0 = *(const float4*)(q0 + k);
                float4 u1 = *(const float4*)(q1 + k);
                float w0 = wp[(size_t)(640 + k + 0) * G4H];
                float w1 = wp[(size_t)(640 + k + 1) * G4H];
                float w2 = wp[(size_t)(640 + k + 2) * G4H];
                float w3 = wp[(size_t)(640 + k + 3) * G4H];
                a0 += w0 * u0.x + w1 * u0.y + w2 * u0.z + w3 * u0.w;
                a1 += w0 * u1.x + w1 * u1.y + w2 * u1.z + w3 * u1.w;
            }
            zbuf[c_idx * 33 + b0r + 0] = a0 + bias;
            zbuf[c_idx * 33 + b0r + 1] = a1 + bias;
            __syncthreads();

            // ---- cell update (gate order i, j, f, o) ----
            if (tid < 256) {
                float zi = zbuf[(0 * 8 + ch) * 33 + cb];
                float zj = zbuf[(1 * 8 + ch) * 33 + cb];
                float zf = zbuf[(2 * 8 + ch) * 33 + cb];
                float zo = zbuf[(3 * 8 + ch) * 33 + cb];
                float cn = sigm(zf + 1.0f) * creg + sigm(zi) * tanhf(zj);
                creg = cn;
                float hv = sigm(zo) * tanhf(cn);
                hws[(size_t)(bid * HB + ch) * Bb + cb] = hv;   // [H][B], coalesced in b
            }
            grid_bar(bar, epoch);   // h complete, visible device-wide

            // ================= projection phase: m' = h @ Pr =================
            if (pact) {
                const int p = p_s + pj;
                const float* pp = Pr + p;
                const int k0 = kq * klen;
                float s = 0.f;
                #pragma unroll 4
                for (int k = k0; k < k0 + klen; ++k) {
                    s += hws[(size_t)k * Bb + cb] * pp[(size_t)k * Pp];
                }
                pred[(pj * 32 + cb) * kq_n + kq] = s;
            }
            __syncthreads();
            if (tid < np * 32) {
                float s = 0.f;
                for (int q2 = 0; q2 < kq_n; ++q2) s += pred[tid * kq_n + q2];
                const int p = p_s + (tid >> 5);
                const int b = tid & 31;
                mnxt[(size_t)b * Pp + p] = s;
                out[((size_t)b * Tt + t) * Pp + p] = s;   // layer0: h0 storage; layer1: final
            }
            grid_bar(bar, epoch);   // m' complete for next step
        }
    }
}

extern "C" void kernel_launch(void* const* d_in, const int* in_sizes, int n_in,
                              void* d_out, int out_size, void* d_ws, size_t ws_size,
                              hipStream_t stream) {
    const float* x   = (const float*)d_in[0];
    const float* W0  = (const float*)d_in[1];
    const float* b0  = (const float*)d_in[2];
    const float* Pr0 = (const float*)d_in[3];
    const float* W1  = (const float*)d_in[4];
    const float* b1  = (const float*)d_in[5];
    const float* Pr1 = (const float*)d_in[6];
    float* out = (float*)d_out;
    float* ws  = (float*)d_ws;

    // zero the barrier counter region (ws is NOT re-poisoned between replays,
    // but the counter must start at 0 every call)
    hipMemsetAsync(d_ws, 0, 256, stream);

    void* args[] = {(void*)&x, (void*)&W0, (void*)&b0, (void*)&Pr0,
                    (void*)&W1, (void*)&b1, (void*)&Pr1, (void*)&out, (void*)&ws};
    hipError_t e = hipLaunchCooperativeKernel((const void*)lstm_persist,
                                              dim3(NBLK), dim3(NTHR), args, 0, stream);
    if (e != hipSuccess) {
        // fallback: 256 blocks x 8 waves trivially co-resident on 256 CUs
        lstm_persist<<<dim3(NBLK), dim3(NTHR), 0, stream>>>(x, W0, b0, Pr0, W1, b1, Pr1, out, ws);
    }
}

// Round 2
// 32099.567 us; speedup vs baseline: 2.5929x; 2.5929x over previous
//
#include <hip/hip_runtime.h>
#include <math.h>

typedef __attribute__((ext_vector_type(8))) short s16x8;
typedef __attribute__((ext_vector_type(16))) float f32x16;

#define NBLK 256
#define NTHR 512

__device__ __forceinline__ float sigm(float v) { return 1.0f / (1.0f + expf(-v)); }

__device__ __forceinline__ unsigned short bf16_rne(float x) {
    unsigned u = __float_as_uint(x);
    return (unsigned short)((u + 0x7FFFu + ((u >> 16) & 1u)) >> 16);
}
// hi = truncated bf16, lo = rne(bf16(x - hi)); hi+lo carries ~16 mantissa bits
__device__ __forceinline__ void split2(float x, unsigned short& hi, unsigned short& lo) {
    unsigned u = __float_as_uint(x);
    hi = (unsigned short)(u >> 16);
    float hf = __uint_as_float(u & 0xFFFF0000u);
    lo = bf16_rne(x - hf);
}

// Grid-wide barrier: monotone counter, agent-scope fences (proved correct in R1).
__device__ __forceinline__ void grid_bar(unsigned int* bar, unsigned int& epoch) {
    __syncthreads();
    epoch++;
    if (threadIdx.x == 0) {
        __threadfence();
        atomicAdd(bar, 1u);
        const unsigned int target = epoch * NBLK;
        while (__hip_atomic_load(bar, __ATOMIC_RELAXED, __HIP_MEMORY_SCOPE_AGENT) < target) {
            __builtin_amdgcn_s_sleep(1);
        }
        __threadfence();
    }
    __syncthreads();
}

// ---------- precompute: transpose [R][C] fp32 -> [C][R] bf16 hi/lo ----------
__global__ void transpose_split(const float* __restrict__ in,
                                unsigned short* __restrict__ outHi,
                                unsigned short* __restrict__ outLo,
                                int R, int C) {
    __shared__ float tile[32][33];
    const int c0 = blockIdx.x * 32;
    const int r0 = blockIdx.y * 32;
    const int tid = threadIdx.x;  // 256
    {
        int r = tid >> 3, q = (tid & 7) * 4;
        const float* p = in + (size_t)(r0 + r) * C + c0 + q;
        float4 v = *(const float4*)p;
        tile[q + 0][r] = v.x; tile[q + 1][r] = v.y;
        tile[q + 2][r] = v.z; tile[q + 3][r] = v.w;
    }
    __syncthreads();
    {
        int c = tid >> 3, q = (tid & 7) * 4;
        ushort4 h, l;
        unsigned short hh, ll;
        split2(tile[c][q + 0], hh, ll); h.x = hh; l.x = ll;
        split2(tile[c][q + 1], hh, ll); h.y = hh; l.y = ll;
        split2(tile[c][q + 2], hh, ll); h.z = hh; l.z = ll;
        split2(tile[c][q + 3], hh, ll); h.w = hh; l.w = ll;
        size_t o = (size_t)(c0 + c) * R + r0 + q;
        *(ushort4*)(outHi + o) = h;
        *(ushort4*)(outLo + o) = l;
    }
}

// ---------- main persistent kernel: split-bf16 MFMA LSTM ----------
__global__ void __launch_bounds__(NTHR, 1) lstm_mfma(
    const float* __restrict__ x,
    const float* __restrict__ bias0, const float* __restrict__ bias1,
    const unsigned short* __restrict__ WH0, const unsigned short* __restrict__ WL0,
    const unsigned short* __restrict__ WH1, const unsigned short* __restrict__ WL1,
    const unsigned short* __restrict__ PH0, const unsigned short* __restrict__ PL0,
    const unsigned short* __restrict__ PH1, const unsigned short* __restrict__ PL1,
    unsigned short* __restrict__ hH, unsigned short* __restrict__ hL,
    unsigned short* __restrict__ mH0, unsigned short* __restrict__ mL0,
    unsigned short* __restrict__ mH1, unsigned short* __restrict__ mL1,
    float* out, unsigned int* bar) {
    __shared__ float part[8][64][16];  // 32 KB: per-wave partial 32x32 tiles
    __shared__ float zb[32][33];       // z exchange [col][batch]

    const int tid = threadIdx.x, bid = blockIdx.x;
    const int wid = tid >> 6, lane = tid & 63;
    const int n = lane & 31, kg = lane >> 5;
    unsigned int epoch = 0;

    // per-lane fixed offsets (elements)
    const size_t wOff  = ((size_t)((n >> 3) * 2048 + bid * 8 + (n & 7))) * 1280 + wid * 160 + kg * 8;
    const size_t aXBase = ((size_t)n * 256) * 640 + wid * 160 + kg * 8;  // + t*640
    const size_t aMOff  = (size_t)n * 640 + ((wid >= 4) ? (wid - 4) * 160 : 0) + kg * 8;
    const size_t hOff   = (size_t)n * 2048 + wid * 256 + kg * 8;
    const size_t pOff   = ((size_t)(bid * 32 + n)) * 2048 + wid * 256 + kg * 8;
    const bool xside = (wid < 4);

    // reduce mapping: D layout col=lane&31, row=(reg&3)+8*(reg>>2)+4*(lane>>5)
    const int rn  = tid >> 4;        // output col-local 0..31
    const int rm0 = (tid & 15) * 2;  // batch rows rm0, rm0+1
    // cell mapping (tid < 256)
    const int ch = tid >> 5, cb = tid & 31;

    for (int layer = 0; layer < 2; ++layer) {
        const float* inp = layer ? (const float*)out : x;
        const unsigned short* WH = layer ? WH1 : WH0;
        const unsigned short* WL = layer ? WL1 : WL0;
        const unsigned short* PH = layer ? PH1 : PH0;
        const unsigned short* PL = layer ? PL1 : PL0;
        const float* bb = layer ? bias1 : bias0;
        const float bv = bb[(rn >> 3) * 2048 + bid * 8 + (rn & 7)];

        for (int i = bid * NTHR + tid; i < 32 * 640; i += NBLK * NTHR) { mH0[i] = 0; mL0[i] = 0; }
        float creg = 0.f;
        grid_bar(bar, epoch);

        for (int t = 0; t < 256; ++t) {
            const unsigned short* mcH = (t & 1) ? mH1 : mH0;
            const unsigned short* mcL = (t & 1) ? mL1 : mL0;
            unsigned short* mnH = (t & 1) ? mH0 : mH1;
            unsigned short* mnL = (t & 1) ? mL0 : mL1;

            // ============ gate GEMM: z[32b][32col], K=1280, 8-wave K-split ============
            f32x16 acc;
            #pragma unroll
            for (int r = 0; r < 16; r++) acc[r] = 0.f;
            const unsigned short* wh = WH + wOff;
            const unsigned short* wl = WL + wOff;
            const float* ax = inp + aXBase + (size_t)t * 640;
            const unsigned short* amH = mcH + aMOff;
            const unsigned short* amL = mcL + aMOff;
            #pragma unroll
            for (int ks = 0; ks < 10; ++ks) {
                s16x8 bh = *(const s16x8*)(wh + ks * 16);
                s16x8 bl = *(const s16x8*)(wl + ks * 16);
                s16x8 ah, al;
                if (xside) {
                    float4 v0 = *(const float4*)(ax + ks * 16);
                    float4 v1 = *(const float4*)(ax + ks * 16 + 4);
                    float f[8] = {v0.x, v0.y, v0.z, v0.w, v1.x, v1.y, v1.z, v1.w};
                    #pragma unroll
                    for (int i = 0; i < 8; i++) {
                        unsigned short h, l;
                        split2(f[i], h, l);
                        ah[i] = (short)h; al[i] = (short)l;
                    }
                } else {
                    ah = *(const s16x8*)(amH + ks * 16);
                    al = *(const s16x8*)(amL + ks * 16);
                }
                acc = __builtin_amdgcn_mfma_f32_32x32x16_bf16(ah, bh, acc, 0, 0, 0);
                acc = __builtin_amdgcn_mfma_f32_32x32x16_bf16(ah, bl, acc, 0, 0, 0);
                acc = __builtin_amdgcn_mfma_f32_32x32x16_bf16(al, bh, acc, 0, 0, 0);
            }
            #pragma unroll
            for (int r = 0; r < 4; r++) {
                float4 v;
                v.x = acc[4 * r + 0]; v.y = acc[4 * r + 1];
                v.z = acc[4 * r + 2]; v.w = acc[4 * r + 3];
                *(float4*)&part[wid][lane][4 * r] = v;
            }
            __syncthreads();
            #pragma unroll
            for (int j = 0; j < 2; j++) {
                int m = rm0 + j;
                int lp = rn + 32 * ((m >> 2) & 1);
                int rg = (m & 3) + 4 * (m >> 3);
                float s = 0.f;
                #pragma unroll
                for (int w = 0; w < 8; w++) s += part[w][lp][rg];
                zb[rn][m] = s + bv;
            }
            __syncthreads();

            // ============ cell update + h write ============
            if (tid < 256) {
                float zi = zb[0 * 8 + ch][cb];
                float zj = zb[1 * 8 + ch][cb];
                float zf = zb[2 * 8 + ch][cb];
                float zo = zb[3 * 8 + ch][cb];
                float cn = sigm(zf + 1.0f) * creg + sigm(zi) * tanhf(zj);
                creg = cn;
                float hv = sigm(zo) * tanhf(cn);
                unsigned short hh, hl;
                split2(hv, hh, hl);
                size_t ho = (size_t)cb * 2048 + bid * 8 + ch;
                hH[ho] = hh; hL[ho] = hl;
            }
            grid_bar(bar, epoch);  // h visible

            // ============ projection: m[32b][32p] on blocks 0..19, K=2048 ============
            if (bid < 20) {
                f32x16 pacc;
                #pragma unroll
                for (int r = 0; r < 16; r++) pacc[r] = 0.f;
                const unsigned short* hhp = hH + hOff;
                const unsigned short* hlp = hL + hOff;
                const unsigned short* php = PH + pOff;
                const unsigned short* plp = PL + pOff;
                #pragma unroll
                for (int ks = 0; ks < 16; ++ks) {
                    s16x8 ahh = *(const s16x8*)(hhp + ks * 16);
                    s16x8 alo = *(const s16x8*)(hlp + ks * 16);
                    s16x8 bhh = *(const s16x8*)(php + ks * 16);
                    s16x8 blo = *(const s16x8*)(plp + ks * 16);
                    pacc = __builtin_amdgcn_mfma_f32_32x32x16_bf16(ahh, bhh, pacc, 0, 0, 0);
                    pacc = __builtin_amdgcn_mfma_f32_32x32x16_bf16(ahh, blo, pacc, 0, 0, 0);
                    pacc = __builtin_amdgcn_mfma_f32_32x32x16_bf16(alo, bhh, pacc, 0, 0, 0);
                }
                #pragma unroll
                for (int r = 0; r < 4; r++) {
                    float4 v;
                    v.x = pacc[4 * r + 0]; v.y = pacc[4 * r + 1];
                    v.z = pacc[4 * r + 2]; v.w = pacc[4 * r + 3];
                    *(float4*)&part[wid][lane][4 * r] = v;
                }
                __syncthreads();
                #pragma unroll
                for (int j = 0; j < 2; j++) {
                    int m = rm0 + j;
                    int lp = rn + 32 * ((m >> 2) & 1);
                    int rg = (m & 3) + 4 * (m >> 3);
                    float s = 0.f;
                    #pragma unroll
                    for (int w = 0; w < 8; w++) s += part[w][lp][rg];
                    int p = bid * 32 + rn;
                    out[((size_t)m * 256 + t) * 640 + p] = s;
                    unsigned short sh, sl;
                    split2(s, sh, sl);
                    mnH[m * 640 + p] = sh;
                    mnL[m * 640 + p] = sl;
                }
            }
            grid_bar(bar, epoch);  // m visible
        }
    }
}

// ---------- fallback (R1 kernel) if ws too small ----------
__global__ void __launch_bounds__(NTHR, 1) lstm_fb(
    const float* __restrict__ x,
    const float* __restrict__ W0, const float* __restrict__ b0, const float* __restrict__ Pr0,
    const float* __restrict__ W1, const float* __restrict__ b1, const float* __restrict__ Pr1,
    float* out, float* ws) {
    const int tid = threadIdx.x;
    const int bid = blockIdx.x;
    unsigned int* bar = (unsigned int*)ws;
    float* mbuf0 = ws + 64;
    float* mbuf1 = mbuf0 + 32 * 640;
    float* hws = mbuf1 + 32 * 640;
    __shared__ float zbuf[32 * 33];
    __shared__ float pred[512];
    unsigned int epoch = 0;
    const int c_idx = tid & 31;
    const int bg = tid >> 5;
    const int b0r = bg * 2;
    const int col = (c_idx >> 3) * 2048 + bid * 8 + (c_idx & 7);
    const int ch = tid >> 5;
    const int cb = tid & 31;
    const int p_s = (bid * 640) / NBLK;
    const int p_e = ((bid + 1) * 640) / NBLK;
    const int np = p_e - p_s;
    const int kq_n = (np == 2) ? 8 : 4;
    const int klen = 2048 / kq_n;
    const int pg = tid >> 5;
    const bool pact = pg < np * kq_n;
    const int pj = pact ? (pg % np) : 0;
    const int kq = pact ? (pg / np) : 0;
    for (int layer = 0; layer < 2; ++layer) {
        const float* W = layer ? W1 : W0;
        const float* bbv = layer ? b1 : b0;
        const float* Pr = layer ? Pr1 : Pr0;
        const float* inb = layer ? (const float*)out : x;
        for (int i = bid * NTHR + tid; i < 32 * 640; i += NBLK * NTHR) mbuf0[i] = 0.0f;
        float creg = 0.0f;
        grid_bar(bar, epoch);
        const float bias = bbv[col];
        for (int t = 0; t < 256; ++t) {
            float* mcur = (t & 1) ? mbuf1 : mbuf0;
            float* mnxt = (t & 1) ? mbuf0 : mbuf1;
            const float* in0 = inb + (size_t)(b0r * 256 + t) * 640;
            const float* in1 = in0 + (size_t)256 * 640;
            const float* wp = W + col;
            float a0 = 0.f, a1 = 0.f;
            #pragma unroll 4
            for (int k = 0; k < 640; k += 4) {
                float4 u0 = *(const float4*)(in0 + k);
                float4 u1 = *(const float4*)(in1 + k);
                float w0 = wp[(size_t)(k + 0) * 8192], w1 = wp[(size_t)(k + 1) * 8192];
                float w2 = wp[(size_t)(k + 2) * 8192], w3 = wp[(size_t)(k + 3) * 8192];
                a0 += w0 * u0.x + w1 * u0.y + w2 * u0.z + w3 * u0.w;
                a1 += w0 * u1.x + w1 * u1.y + w2 * u1.z + w3 * u1.w;
            }
            const float* q0 = mcur + (size_t)b0r * 640;
            const float* q1 = q0 + 640;
            #pragma unroll 4
            for (int k = 0; k < 640; k += 4) {
                float4 u0 = *(const float4*)(q0 + k);
                float4 u1 = *(const float4*)(q1 + k);
                float w0 = wp[(size_t)(640 + k + 0) * 8192], w1 = wp[(size_t)(640 + k + 1) * 8192];
                float w2 = wp[(size_t)(640 + k + 2) * 8192], w3 = wp[(size_t)(640 + k + 3) * 8192];
                a0 += w0 * u0.x + w1 * u0.y + w2 * u0.z + w3 * u0.w;
                a1 += w0 * u1.x + w1 * u1.y + w2 * u1.z + w3 * u1.w;
            }
            zbuf[c_idx * 33 + b0r + 0] = a0 + bias;
            zbuf[c_idx * 33 + b0r + 1] = a1 + bias;
            __syncthreads();
            if (tid < 256) {
                float zi = zbuf[(0 * 8 + ch) * 33 + cb];
                float zj = zbuf[(1 * 8 + ch) * 33 + cb];
                float zf = zbuf[(2 * 8 + ch) * 33 + cb];
                float zo = zbuf[(3 * 8 + ch) * 33 + cb];
                float cn = sigm(zf + 1.0f) * creg + sigm(zi) * tanhf(zj);
                creg = cn;
                hws[(size_t)(bid * 8 + ch) * 32 + cb] = sigm(zo) * tanhf(cn);
            }
            grid_bar(bar, epoch);
            if (pact) {
                const int p = p_s + pj;
                const float* pp = Pr + p;
                const int k0 = kq * klen;
                float s = 0.f;
                #pragma unroll 4
                for (int k = k0; k < k0 + klen; ++k) s += hws[(size_t)k * 32 + cb] * pp[(size_t)k * 640];
                pred[(pj * 32 + cb) * kq_n + kq] = s;
            }
            __syncthreads();
            if (tid < np * 32) {
                float s = 0.f;
                for (int q2 = 0; q2 < kq_n; ++q2) s += pred[tid * kq_n + q2];
                const int p = p_s + (tid >> 5);
                const int b = tid & 31;
                mnxt[(size_t)b * 640 + p] = s;
                out[((size_t)b * 256 + t) * 640 + p] = s;
            }
            grid_bar(bar, epoch);
        }
    }
}

extern "C" void kernel_launch(void* const* d_in, const int* in_sizes, int n_in,
                              void* d_out, int out_size, void* d_ws, size_t ws_size,
                              hipStream_t stream) {
    const float* x   = (const float*)d_in[0];
    const float* W0  = (const float*)d_in[1];
    const float* b0  = (const float*)d_in[2];
    const float* P0  = (const float*)d_in[3];
    const float* W1  = (const float*)d_in[4];
    const float* b1  = (const float*)d_in[5];
    const float* P1  = (const float*)d_in[6];
    float* out = (float*)d_out;

    // ws layout (bytes, 256-aligned chunks)
    size_t off = 0;
    auto alloc = [&](size_t bytes) { size_t o = off; off += (bytes + 255) & ~(size_t)255; return o; };
    const size_t oBar = alloc(256);
    const size_t szW = (size_t)8192 * 1280 * 2;   // bf16 [8192][1280]
    const size_t szP = (size_t)640 * 2048 * 2;    // bf16 [640][2048]
    const size_t oWH0 = alloc(szW), oWL0 = alloc(szW), oWH1 = alloc(szW), oWL1 = alloc(szW);
    const size_t oPH0 = alloc(szP), oPL0 = alloc(szP), oPH1 = alloc(szP), oPL1 = alloc(szP);
    const size_t szH = (size_t)32 * 2048 * 2;
    const size_t oHH = alloc(szH), oHL = alloc(szH);
    const size_t szM = (size_t)32 * 640 * 2;
    const size_t oMH0 = alloc(szM), oML0 = alloc(szM), oMH1 = alloc(szM), oML1 = alloc(szM);
    const size_t need = off;

    hipMemsetAsync(d_ws, 0, 256, stream);  // barrier counter

    if (ws_size < need) {  // fallback: R1 kernel (~0.5 MB ws)
        float* ws = (float*)d_ws;
        void* args[] = {(void*)&x, (void*)&W0, (void*)&b0, (void*)&P0,
                        (void*)&W1, (void*)&b1, (void*)&P1, (void*)&out, (void*)&ws};
        hipError_t e = hipLaunchCooperativeKernel((const void*)lstm_fb,
                                                  dim3(NBLK), dim3(NTHR), args, 0, stream);
        if (e != hipSuccess)
            lstm_fb<<<dim3(NBLK), dim3(NTHR), 0, stream>>>(x, W0, b0, P0, W1, b1, P1, out, ws);
        return;
    }

    char* w = (char*)d_ws;
    unsigned short *WH0p = (unsigned short*)(w + oWH0), *WL0p = (unsigned short*)(w + oWL0);
    unsigned short *WH1p = (unsigned short*)(w + oWH1), *WL1p = (unsigned short*)(w + oWL1);
    unsigned short *PH0p = (unsigned short*)(w + oPH0), *PL0p = (unsigned short*)(w + oPL0);
    unsigned short *PH1p = (unsigned short*)(w + oPH1), *PL1p = (unsigned short*)(w + oPL1);
    unsigned short *hHp = (unsigned short*)(w + oHH), *hLp = (unsigned short*)(w + oHL);
    unsigned short *mH0p = (unsigned short*)(w + oMH0), *mL0p = (unsigned short*)(w + oML0);
    unsigned short *mH1p = (unsigned short*)(w + oMH1), *mL1p = (unsigned short*)(w + oML1);
    unsigned int* barp = (unsigned int*)(w + oBar);

    // precompute: transpose+split weights
    transpose_split<<<dim3(8192 / 32, 1280 / 32), 256, 0, stream>>>(W0, WH0p, WL0p, 1280, 8192);
    transpose_split<<<dim3(8192 / 32, 1280 / 32), 256, 0, stream>>>(W1, WH1p, WL1p, 1280, 8192);
    transpose_split<<<dim3(640 / 32, 2048 / 32), 256, 0, stream>>>(P0, PH0p, PL0p, 2048, 640);
    transpose_split<<<dim3(640 / 32, 2048 / 32), 256, 0, stream>>>(P1, PH1p, PL1p, 2048, 640);

    const float *b0c = b0, *b1c = b1;
    void* args[] = {(void*)&x, (void*)&b0c, (void*)&b1c,
                    (void*)&WH0p, (void*)&WL0p, (void*)&WH1p, (void*)&WL1p,
                    (void*)&PH0p, (void*)&PL0p, (void*)&PH1p, (void*)&PL1p,
                    (void*)&hHp, (void*)&hLp,
                    (void*)&mH0p, (void*)&mL0p, (void*)&mH1p, (void*)&mL1p,
                    (void*)&out, (void*)&barp};
    hipError_t e = hipLaunchCooperativeKernel((const void*)lstm_mfma,
                                              dim3(NBLK), dim3(NTHR), args, 0, stream);
    if (e != hipSuccess)
        lstm_mfma<<<dim3(NBLK), dim3(NTHR), 0, stream>>>(
            x, b0c, b1c, WH0p, WL0p, WH1p, WL1p, PH0p, PL0p, PH1p, PL1p,
            hHp, hLp, mH0p, mL0p, mH1p, mL1p, out, barp);
}

// Round 3
// 27219.177 us; speedup vs baseline: 3.0578x; 1.1793x over previous
//
#include <hip/hip_runtime.h>
#include <math.h>

typedef __attribute__((ext_vector_type(8))) short s16x8;
typedef __attribute__((ext_vector_type(16))) float f32x16;
typedef unsigned long long u64;

#define NBLK 256
#define NTHR 512
#define AGG_BID (NBLK - 1)

__device__ __forceinline__ float sigm(float v) { return 1.0f / (1.0f + expf(-v)); }

__device__ __forceinline__ unsigned short bf16_rne(float x) {
    unsigned u = __float_as_uint(x);
    return (unsigned short)((u + 0x7FFFu + ((u >> 16) & 1u)) >> 16);
}
// hi = truncated bf16, lo = rne(bf16(x - hi)); hi+lo carries ~16 mantissa bits
__device__ __forceinline__ void split2(float x, unsigned short& hi, unsigned short& lo) {
    unsigned u = __float_as_uint(x);
    hi = (unsigned short)(u >> 16);
    float hf = __uint_as_float(u & 0xFFFF0000u);
    lo = bf16_rne(x - hf);
}

// ---- device-scope (L2-bypassing) loads for cross-block data ----
__device__ __forceinline__ u64 ald64(const void* p) {
    return __hip_atomic_load((const u64*)p, __ATOMIC_RELAXED, __HIP_MEMORY_SCOPE_AGENT);
}
__device__ __forceinline__ s16x8 ald_frag16(const unsigned short* p) {
    union { u64 q[2]; s16x8 v; } u;
    u.q[0] = ald64(p);
    u.q[1] = ald64(p + 4);
    return u.v;
}

// ---- fast flag-tree grid barrier: no atomic RMW, no L2 invalidation ----
// Writers: release-fence (wbL2) + arrive store. Aggregator (block AGG_BID,
// wave 0) polls all 256 slots, publishes release. Pollers read release only;
// cross-block data is read via agent-scope loads, so no acquire-inv needed.
__device__ __forceinline__ void gbar(unsigned* arr, unsigned* rel, unsigned& epoch) {
    __syncthreads();
    const unsigned e = ++epoch;
    if (blockIdx.x == AGG_BID) {
        if (threadIdx.x < 64) {
            if (threadIdx.x == 0) {
                __builtin_amdgcn_fence(__ATOMIC_RELEASE, "agent");
                __hip_atomic_store(arr + AGG_BID, e, __ATOMIC_RELAXED, __HIP_MEMORY_SCOPE_AGENT);
            }
            const int i0 = (int)threadIdx.x * 4;
            for (;;) {
                unsigned a0 = __hip_atomic_load(arr + i0 + 0, __ATOMIC_RELAXED, __HIP_MEMORY_SCOPE_AGENT);
                unsigned a1 = __hip_atomic_load(arr + i0 + 1, __ATOMIC_RELAXED, __HIP_MEMORY_SCOPE_AGENT);
                unsigned a2 = __hip_atomic_load(arr + i0 + 2, __ATOMIC_RELAXED, __HIP_MEMORY_SCOPE_AGENT);
                unsigned a3 = __hip_atomic_load(arr + i0 + 3, __ATOMIC_RELAXED, __HIP_MEMORY_SCOPE_AGENT);
                bool ok = (a0 >= e) && (a1 >= e) && (a2 >= e) && (a3 >= e);
                if (__all(ok)) break;
                __builtin_amdgcn_s_sleep(1);
            }
            if (threadIdx.x == 0)
                __hip_atomic_store(rel, e, __ATOMIC_RELAXED, __HIP_MEMORY_SCOPE_AGENT);
        }
        __syncthreads();
    } else {
        if (threadIdx.x == 0) {
            __builtin_amdgcn_fence(__ATOMIC_RELEASE, "agent");
            __hip_atomic_store(arr + blockIdx.x, e, __ATOMIC_RELAXED, __HIP_MEMORY_SCOPE_AGENT);
            while (__hip_atomic_load(rel, __ATOMIC_RELAXED, __HIP_MEMORY_SCOPE_AGENT) < e)
                __builtin_amdgcn_s_sleep(2);
        }
        __syncthreads();
    }
}

// ---------- precompute: transpose [R][C] fp32 -> [C][R] bf16 hi/lo ----------
__global__ void transpose_split(const float* __restrict__ in,
                                unsigned short* __restrict__ outHi,
                                unsigned short* __restrict__ outLo,
                                int R, int C) {
    __shared__ float tile[32][33];
    const int c0 = blockIdx.x * 32;
    const int r0 = blockIdx.y * 32;
    const int tid = threadIdx.x;  // 256
    {
        int r = tid >> 3, q = (tid & 7) * 4;
        const float* p = in + (size_t)(r0 + r) * C + c0 + q;
        float4 v = *(const float4*)p;
        tile[q + 0][r] = v.x; tile[q + 1][r] = v.y;
        tile[q + 2][r] = v.z; tile[q + 3][r] = v.w;
    }
    __syncthreads();
    {
        int c = tid >> 3, q = (tid & 7) * 4;
        ushort4 h, l;
        unsigned short hh, ll;
        split2(tile[c][q + 0], hh, ll); h.x = hh; l.x = ll;
        split2(tile[c][q + 1], hh, ll); h.y = hh; l.y = ll;
        split2(tile[c][q + 2], hh, ll); h.z = hh; l.z = ll;
        split2(tile[c][q + 3], hh, ll); h.w = hh; l.w = ll;
        size_t o = (size_t)(c0 + c) * R + r0 + q;
        *(ushort4*)(outHi + o) = h;
        *(ushort4*)(outLo + o) = l;
    }
}

// x-part of the gate GEMM: 5 k-steps over this wave's 80-k slice of K=640.
// l0: input is fp32 x (cached loads); else fp32 `out` (agent-scope loads).
__device__ __forceinline__ f32x16 gate_xpart(const float* xb, const unsigned short* whx,
                                             const unsigned short* wlx, bool l0) {
    f32x16 a;
    #pragma unroll
    for (int r = 0; r < 16; ++r) a[r] = 0.f;
    #pragma unroll
    for (int ks = 0; ks < 5; ++ks) {
        s16x8 bh = *(const s16x8*)(whx + ks * 16);
        s16x8 bl = *(const s16x8*)(wlx + ks * 16);
        float f[8];
        if (l0) {
            float4 v0 = *(const float4*)(xb + ks * 16);
            float4 v1 = *(const float4*)(xb + ks * 16 + 4);
            f[0] = v0.x; f[1] = v0.y; f[2] = v0.z; f[3] = v0.w;
            f[4] = v1.x; f[5] = v1.y; f[6] = v1.z; f[7] = v1.w;
        } else {
            #pragma unroll
            for (int i = 0; i < 4; ++i) {
                union { u64 q; float g[2]; } u;
                u.q = ald64(xb + ks * 16 + 2 * i);
                f[2 * i] = u.g[0]; f[2 * i + 1] = u.g[1];
            }
        }
        s16x8 ah, al;
        #pragma unroll
        for (int i = 0; i < 8; ++i) {
            unsigned short h, l;
            split2(f[i], h, l);
            ah[i] = (short)h; al[i] = (short)l;
        }
        a = __builtin_amdgcn_mfma_f32_32x32x16_bf16(ah, bh, a, 0, 0, 0);
        a = __builtin_amdgcn_mfma_f32_32x32x16_bf16(ah, bl, a, 0, 0, 0);
        a = __builtin_amdgcn_mfma_f32_32x32x16_bf16(al, bh, a, 0, 0, 0);
    }
    return a;
}

// ---------- main persistent kernel ----------
__global__ void __launch_bounds__(NTHR, 1) lstm_mfma(
    const float* __restrict__ x,
    const float* __restrict__ bias0, const float* __restrict__ bias1,
    const unsigned short* __restrict__ WH0, const unsigned short* __restrict__ WL0,
    const unsigned short* __restrict__ WH1, const unsigned short* __restrict__ WL1,
    const unsigned short* __restrict__ PH0, const unsigned short* __restrict__ PL0,
    const unsigned short* __restrict__ PH1, const unsigned short* __restrict__ PL1,
    unsigned short* __restrict__ hH, unsigned short* __restrict__ hL,
    unsigned short* __restrict__ mH0, unsigned short* __restrict__ mL0,
    unsigned short* __restrict__ mH1, unsigned short* __restrict__ mL1,
    float* out, unsigned* arr, unsigned* rel) {
    __shared__ float part[8][64][20];  // padded stride: 16B-aligned, bank-spread
    __shared__ float zb[32][33];

    const int tid = threadIdx.x, bid = blockIdx.x;
    const int wid = tid >> 6, lane = tid & 63;
    const int n = lane & 31, kg = lane >> 5;
    unsigned epoch = 0;

    const int col = (n >> 3) * 2048 + bid * 8 + (n & 7);
    const size_t wOffX = (size_t)col * 1280 + wid * 80 + kg * 8;  // x-part k-slice
    const size_t wOffM = wOffX + 640;                             // m-part k-slice
    const size_t aXOff = (size_t)n * (256 * 640) + wid * 80 + kg * 8;  // + t*640
    const size_t aMOff = (size_t)n * 640 + wid * 80 + kg * 8;
    const size_t hOff  = (size_t)n * 2048 + wid * 256 + kg * 8;
    const size_t pOff  = ((size_t)(bid * 32 + n)) * 2048 + wid * 256 + kg * 8;

    // reduce mapping: D col=lane&31, row=(reg&3)+8*(reg>>2)+4*(lane>>5)
    const int rn  = tid >> 4;
    const int rm0 = (tid & 15) * 2;
    const int ch = tid >> 5, cb = tid & 31;  // cell mapping (tid<256)

    for (int layer = 0; layer < 2; ++layer) {
        const bool l0 = (layer == 0);
        const float* inp = l0 ? x : (const float*)out;
        const unsigned short* WH = l0 ? WH0 : WH1;
        const unsigned short* WL = l0 ? WL0 : WL1;
        const unsigned short* PH = l0 ? PH0 : PH1;
        const unsigned short* PL = l0 ? PL0 : PL1;
        const float* bb = l0 ? bias0 : bias1;
        const float bv = bb[(rn >> 3) * 2048 + bid * 8 + (rn & 7)];

        for (int i = bid * NTHR + tid; i < 32 * 640; i += NBLK * NTHR) { mH0[i] = 0; mL0[i] = 0; }
        float creg = 0.f;
        gbar(arr, rel, epoch);  // m0 zeros + (layer1) full `out` visible

        // x-part for t=0
        f32x16 zacc = gate_xpart(inp + aXOff, WH + wOffX, WL + wOffX, l0);

        for (int t = 0; t < 256; ++t) {
            const unsigned short* mcH = (t & 1) ? mH1 : mH0;
            const unsigned short* mcL = (t & 1) ? mL1 : mL0;
            unsigned short* mnH = (t & 1) ? mH0 : mH1;
            unsigned short* mnL = (t & 1) ? mL0 : mL1;

            // ===== phase A: gate m-part (K=640 over 8 waves), on top of carried x-part =====
            f32x16 acc = zacc;
            {
                const unsigned short* whm = WH + wOffM;
                const unsigned short* wlm = WL + wOffM;
                const unsigned short* pmH = mcH + aMOff;
                const unsigned short* pmL = mcL + aMOff;
                #pragma unroll
                for (int ks = 0; ks < 5; ++ks) {
                    s16x8 bh = *(const s16x8*)(whm + ks * 16);
                    s16x8 bl = *(const s16x8*)(wlm + ks * 16);
                    s16x8 ah = ald_frag16(pmH + ks * 16);
                    s16x8 al = ald_frag16(pmL + ks * 16);
                    acc = __builtin_amdgcn_mfma_f32_32x32x16_bf16(ah, bh, acc, 0, 0, 0);
                    acc = __builtin_amdgcn_mfma_f32_32x32x16_bf16(ah, bl, acc, 0, 0, 0);
                    acc = __builtin_amdgcn_mfma_f32_32x32x16_bf16(al, bh, acc, 0, 0, 0);
                }
            }
            #pragma unroll
            for (int r = 0; r < 4; r++) {
                float4 v;
                v.x = acc[4 * r + 0]; v.y = acc[4 * r + 1];
                v.z = acc[4 * r + 2]; v.w = acc[4 * r + 3];
                *(float4*)&part[wid][lane][4 * r] = v;
            }
            __syncthreads();
            #pragma unroll
            for (int j = 0; j < 2; j++) {
                int m = rm0 + j;
                int lp = rn + 32 * ((m >> 2) & 1);
                int rg = (m & 3) + 4 * (m >> 3);
                float s = 0.f;
                #pragma unroll
                for (int w = 0; w < 8; w++) s += part[w][lp][rg];
                zb[rn][m] = s + bv;
            }
            __syncthreads();

            // ===== cell update + h write (gate order i, j, f, o) =====
            if (tid < 256) {
                float zi = zb[0 * 8 + ch][cb];
                float zj = zb[1 * 8 + ch][cb];
                float zf = zb[2 * 8 + ch][cb];
                float zo = zb[3 * 8 + ch][cb];
                float cn = sigm(zf + 1.0f) * creg + sigm(zi) * tanhf(zj);
                creg = cn;
                float hv = sigm(zo) * tanhf(cn);
                unsigned short hh, hl;
                split2(hv, hh, hl);
                size_t ho = (size_t)cb * 2048 + bid * 8 + ch;
                hH[ho] = hh; hL[ho] = hl;
            }
            gbar(arr, rel, epoch);  // BAR1: h visible

            // ===== phase B: projection (blocks 0..19) || x-part(t+1) (everyone) =====
            if (bid < 20) {
                f32x16 pacc;
                #pragma unroll
                for (int r = 0; r < 16; r++) pacc[r] = 0.f;
                const unsigned short* hhp = hH + hOff;
                const unsigned short* hlp = hL + hOff;
                const unsigned short* php = PH + pOff;
                const unsigned short* plp = PL + pOff;
                #pragma unroll
                for (int ks = 0; ks < 16; ++ks) {
                    s16x8 ahh = ald_frag16(hhp + ks * 16);
                    s16x8 alo = ald_frag16(hlp + ks * 16);
                    s16x8 bhh = *(const s16x8*)(php + ks * 16);
                    s16x8 blo = *(const s16x8*)(plp + ks * 16);
                    pacc = __builtin_amdgcn_mfma_f32_32x32x16_bf16(ahh, bhh, pacc, 0, 0, 0);
                    pacc = __builtin_amdgcn_mfma_f32_32x32x16_bf16(ahh, blo, pacc, 0, 0, 0);
                    pacc = __builtin_amdgcn_mfma_f32_32x32x16_bf16(alo, bhh, pacc, 0, 0, 0);
                }
                #pragma unroll
                for (int r = 0; r < 4; r++) {
                    float4 v;
                    v.x = pacc[4 * r + 0]; v.y = pacc[4 * r + 1];
                    v.z = pacc[4 * r + 2]; v.w = pacc[4 * r + 3];
                    *(float4*)&part[wid][lane][4 * r] = v;
                }
                __syncthreads();
                #pragma unroll
                for (int j = 0; j < 2; j++) {
                    int m = rm0 + j;
                    int lp = rn + 32 * ((m >> 2) & 1);
                    int rg = (m & 3) + 4 * (m >> 3);
                    float s = 0.f;
                    #pragma unroll
                    for (int w = 0; w < 8; w++) s += part[w][lp][rg];
                    int p = bid * 32 + rn;
                    out[((size_t)m * 256 + t) * 640 + p] = s;
                    unsigned short sh, sl;
                    split2(s, sh, sl);
                    mnH[m * 640 + p] = sh;
                    mnL[m * 640 + p] = sl;
                }
            }
            if (t < 255)
                zacc = gate_xpart(inp + aXOff + (size_t)(t + 1) * 640,
                                  WH + wOffX, WL + wOffX, l0);
            gbar(arr, rel, epoch);  // BAR2: m(t+1) visible
        }
    }
}

// ---------- fallback (R1-style) if ws too small ----------
__device__ __forceinline__ void grid_bar_slow(unsigned int* bar, unsigned int& epoch) {
    __syncthreads();
    epoch++;
    if (threadIdx.x == 0) {
        __threadfence();
        atomicAdd(bar, 1u);
        const unsigned int target = epoch * NBLK;
        while (__hip_atomic_load(bar, __ATOMIC_RELAXED, __HIP_MEMORY_SCOPE_AGENT) < target) {
            __builtin_amdgcn_s_sleep(1);
        }
        __threadfence();
    }
    __syncthreads();
}

__global__ void __launch_bounds__(NTHR, 1) lstm_fb(
    const float* __restrict__ x,
    const float* __restrict__ W0, const float* __restrict__ b0, const float* __restrict__ Pr0,
    const float* __restrict__ W1, const float* __restrict__ b1, const float* __restrict__ Pr1,
    float* out, float* ws) {
    const int tid = threadIdx.x;
    const int bid = blockIdx.x;
    unsigned int* bar = (unsigned int*)ws;
    float* mbuf0 = ws + 1024;
    float* mbuf1 = mbuf0 + 32 * 640;
    float* hws = mbuf1 + 32 * 640;
    __shared__ float zbuf[32 * 33];
    __shared__ float pred[512];
    unsigned int epoch = 0;
    const int c_idx = tid & 31;
    const int bg = tid >> 5;
    const int b0r = bg * 2;
    const int col = (c_idx >> 3) * 2048 + bid * 8 + (c_idx & 7);
    const int ch = tid >> 5;
    const int cb = tid & 31;
    const int p_s = (bid * 640) / NBLK;
    const int p_e = ((bid + 1) * 640) / NBLK;
    const int np = p_e - p_s;
    const int kq_n = (np == 2) ? 8 : 4;
    const int klen = 2048 / kq_n;
    const int pg = tid >> 5;
    const bool pact = pg < np * kq_n;
    const int pj = pact ? (pg % np) : 0;
    const int kq = pact ? (pg / np) : 0;
    for (int layer = 0; layer < 2; ++layer) {
        const float* W = layer ? W1 : W0;
        const float* bbv = layer ? b1 : b0;
        const float* Pr = layer ? Pr1 : Pr0;
        const float* inb = layer ? (const float*)out : x;
        for (int i = bid * NTHR + tid; i < 32 * 640; i += NBLK * NTHR) mbuf0[i] = 0.0f;
        float creg = 0.0f;
        grid_bar_slow(bar, epoch);
        const float bias = bbv[col];
        for (int t = 0; t < 256; ++t) {
            float* mcur = (t & 1) ? mbuf1 : mbuf0;
            float* mnxt = (t & 1) ? mbuf0 : mbuf1;
            const float* in0 = inb + (size_t)(b0r * 256 + t) * 640;
            const float* in1 = in0 + (size_t)256 * 640;
            const float* wp = W + col;
            float a0 = 0.f, a1 = 0.f;
            #pragma unroll 4
            for (int k = 0; k < 640; k += 4) {
                float4 u0 = *(const float4*)(in0 + k);
                float4 u1 = *(const float4*)(in1 + k);
                float w0 = wp[(size_t)(k + 0) * 8192], w1 = wp[(size_t)(k + 1) * 8192];
                float w2 = wp[(size_t)(k + 2) * 8192], w3 = wp[(size_t)(k + 3) * 8192];
                a0 += w0 * u0.x + w1 * u0.y + w2 * u0.z + w3 * u0.w;
                a1 += w0 * u1.x + w1 * u1.y + w2 * u1.z + w3 * u1.w;
            }
            const float* q0 = mcur + (size_t)b0r * 640;
            const float* q1 = q0 + 640;
            #pragma unroll 4
            for (int k = 0; k < 640; k += 4) {
                float4 u0 = *(const float4*)(q0 + k);
                float4 u1 = *(const float4*)(q1 + k);
                float w0 = wp[(size_t)(640 + k + 0) * 8192], w1 = wp[(size_t)(640 + k + 1) * 8192];
                float w2 = wp[(size_t)(640 + k + 2) * 8192], w3 = wp[(size_t)(640 + k + 3) * 8192];
                a0 += w0 * u0.x + w1 * u0.y + w2 * u0.z + w3 * u0.w;
                a1 += w0 * u1.x + w1 * u1.y + w2 * u1.z + w3 * u1.w;
            }
            zbuf[c_idx * 33 + b0r + 0] = a0 + bias;
            zbuf[c_idx * 33 + b0r + 1] = a1 + bias;
            __syncthreads();
            if (tid < 256) {
                float zi = zbuf[(0 * 8 + ch) * 33 + cb];
                float zj = zbuf[(1 * 8 + ch) * 33 + cb];
                float zf = zbuf[(2 * 8 + ch) * 33 + cb];
                float zo = zbuf[(3 * 8 + ch) * 33 + cb];
                float cn = sigm(zf + 1.0f) * creg + sigm(zi) * tanhf(zj);
                creg = cn;
                hws[(size_t)(bid * 8 + ch) * 32 + cb] = sigm(zo) * tanhf(cn);
            }
            grid_bar_slow(bar, epoch);
            if (pact) {
                const int p = p_s + pj;
                const float* pp = Pr + p;
                const int k0 = kq * klen;
                float s = 0.f;
                #pragma unroll 4
                for (int k = k0; k < k0 + klen; ++k) s += hws[(size_t)k * 32 + cb] * pp[(size_t)k * 640];
                pred[(pj * 32 + cb) * kq_n + kq] = s;
            }
            __syncthreads();
            if (tid < np * 32) {
                float s = 0.f;
                for (int q2 = 0; q2 < kq_n; ++q2) s += pred[tid * kq_n + q2];
                const int p = p_s + (tid >> 5);
                const int b = tid & 31;
                mnxt[(size_t)b * 640 + p] = s;
                out[((size_t)b * 256 + t) * 640 + p] = s;
            }
            grid_bar_slow(bar, epoch);
        }
    }
}

extern "C" void kernel_launch(void* const* d_in, const int* in_sizes, int n_in,
                              void* d_out, int out_size, void* d_ws, size_t ws_size,
                              hipStream_t stream) {
    const float* x   = (const float*)d_in[0];
    const float* W0  = (const float*)d_in[1];
    const float* b0  = (const float*)d_in[2];
    const float* P0  = (const float*)d_in[3];
    const float* W1  = (const float*)d_in[4];
    const float* b1  = (const float*)d_in[5];
    const float* P1  = (const float*)d_in[6];
    float* out = (float*)d_out;

    // ws layout (bytes, 256-aligned chunks)
    size_t off = 0;
    auto alloc = [&](size_t bytes) { size_t o = off; off += (bytes + 255) & ~(size_t)255; return o; };
    const size_t oBar = alloc(4096);              // arrive[256] @0, release @2048
    const size_t szW = (size_t)8192 * 1280 * 2;   // bf16 [8192][1280]
    const size_t szP = (size_t)640 * 2048 * 2;    // bf16 [640][2048]
    const size_t oWH0 = alloc(szW), oWL0 = alloc(szW), oWH1 = alloc(szW), oWL1 = alloc(szW);
    const size_t oPH0 = alloc(szP), oPL0 = alloc(szP), oPH1 = alloc(szP), oPL1 = alloc(szP);
    const size_t szH = (size_t)32 * 2048 * 2;
    const size_t oHH = alloc(szH), oHL = alloc(szH);
    const size_t szM = (size_t)32 * 640 * 2;
    const size_t oMH0 = alloc(szM), oML0 = alloc(szM), oMH1 = alloc(szM), oML1 = alloc(szM);
    const size_t need = off;

    hipMemsetAsync(d_ws, 0, 4096, stream);  // barrier flags must start at 0 every call

    if (ws_size < need) {  // fallback path (~0.5 MB ws)
        float* ws = (float*)d_ws;
        void* args[] = {(void*)&x, (void*)&W0, (void*)&b0, (void*)&P0,
                        (void*)&W1, (void*)&b1, (void*)&P1, (void*)&out, (void*)&ws};
        hipError_t e = hipLaunchCooperativeKernel((const void*)lstm_fb,
                                                  dim3(NBLK), dim3(NTHR), args, 0, stream);
        if (e != hipSuccess)
            lstm_fb<<<dim3(NBLK), dim3(NTHR), 0, stream>>>(x, W0, b0, P0, W1, b1, P1, out, ws);
        return;
    }

    char* w = (char*)d_ws;
    unsigned short *WH0p = (unsigned short*)(w + oWH0), *WL0p = (unsigned short*)(w + oWL0);
    unsigned short *WH1p = (unsigned short*)(w + oWH1), *WL1p = (unsigned short*)(w + oWL1);
    unsigned short *PH0p = (unsigned short*)(w + oPH0), *PL0p = (unsigned short*)(w + oPL0);
    unsigned short *PH1p = (unsigned short*)(w + oPH1), *PL1p = (unsigned short*)(w + oPL1);
    unsigned short *hHp = (unsigned short*)(w + oHH), *hLp = (unsigned short*)(w + oHL);
    unsigned short *mH0p = (unsigned short*)(w + oMH0), *mL0p = (unsigned short*)(w + oML0);
    unsigned short *mH1p = (unsigned short*)(w + oMH1), *mL1p = (unsigned short*)(w + oML1);
    unsigned *arrp = (unsigned*)(w + oBar);
    unsigned *relp = (unsigned*)(w + oBar + 2048);

    // precompute: transpose+split weights (runs inside the graph every call; ~40 µs)
    transpose_split<<<dim3(8192 / 32, 1280 / 32), 256, 0, stream>>>(W0, WH0p, WL0p, 1280, 8192);
    transpose_split<<<dim3(8192 / 32, 1280 / 32), 256, 0, stream>>>(W1, WH1p, WL1p, 1280, 8192);
    transpose_split<<<dim3(640 / 32, 2048 / 32), 256, 0, stream>>>(P0, PH0p, PL0p, 2048, 640);
    transpose_split<<<dim3(640 / 32, 2048 / 32), 256, 0, stream>>>(P1, PH1p, PL1p, 2048, 640);

    const float *b0c = b0, *b1c = b1;
    void* args[] = {(void*)&x, (void*)&b0c, (void*)&b1c,
                    (void*)&WH0p, (void*)&WL0p, (void*)&WH1p, (void*)&WL1p,
                    (void*)&PH0p, (void*)&PL0p, (void*)&PH1p, (void*)&PL1p,
                    (void*)&hHp, (void*)&hLp,
                    (void*)&mH0p, (void*)&mL0p, (void*)&mH1p, (void*)&mL1p,
                    (void*)&out, (void*)&arrp, (void*)&relp};
    hipError_t e = hipLaunchCooperativeKernel((const void*)lstm_mfma,
                                              dim3(NBLK), dim3(NTHR), args, 0, stream);
    if (e != hipSuccess)
        lstm_mfma<<<dim3(NBLK), dim3(NTHR), 0, stream>>>(
            x, b0c, b1c, WH0p, WL0p, WH1p, WL1p, PH0p, PL0p, PH1p, PL1p,
            hHp, hLp, mH0p, mL0p, mH1p, mL1p, out, arrp, relp);
}

// Round 4
// 21269.963 us; speedup vs baseline: 3.9130x; 1.2797x over previous
//
#include <hip/hip_runtime.h>
#include <math.h>

typedef __attribute__((ext_vector_type(8))) short s16x8;
typedef __attribute__((ext_vector_type(16))) float f32x16;
typedef unsigned long long u64;

#define NBLK 256
#define NTHR 512
#define NPROJ 20

__device__ __forceinline__ float sigm(float v) { return 1.0f / (1.0f + expf(-v)); }

__device__ __forceinline__ unsigned short bf16_rne(float x) {
    unsigned u = __float_as_uint(x);
    return (unsigned short)((u + 0x7FFFu + ((u >> 16) & 1u)) >> 16);
}
// hi = truncated bf16, lo = rne(bf16(x - hi)); hi+lo carries ~16 mantissa bits
__device__ __forceinline__ void split2(float x, unsigned short& hi, unsigned short& lo) {
    unsigned u = __float_as_uint(x);
    hi = (unsigned short)(u >> 16);
    float hf = __uint_as_float(u & 0xFFFF0000u);
    lo = bf16_rne(x - hf);
}

// ---- agent-scope (coherence-point) accessors for cross-block data ----
__device__ __forceinline__ u64 ald64(const void* p) {
    return __hip_atomic_load((const u64*)p, __ATOMIC_RELAXED, __HIP_MEMORY_SCOPE_AGENT);
}
__device__ __forceinline__ void ast32(float* p, float v) {
    __hip_atomic_store((unsigned*)p, __float_as_uint(v), __ATOMIC_RELAXED, __HIP_MEMORY_SCOPE_AGENT);
}
__device__ __forceinline__ void ld8f(const float* p, float* f) {
    #pragma unroll
    for (int i = 0; i < 4; ++i) {
        union { u64 q; float g[2]; } u;
        u.q = ald64(p + 2 * i);
        f[2 * i] = u.g[0]; f[2 * i + 1] = u.g[1];
    }
}
__device__ __forceinline__ void split8(const float* f, s16x8& h, s16x8& l) {
    #pragma unroll
    for (int i = 0; i < 8; ++i) {
        unsigned short hh, ll;
        split2(f[i], hh, ll);
        h[i] = (short)hh; l[i] = (short)ll;
    }
}

// ---- barrier polls (callers gate on threadIdx.x < 64 and follow with __syncthreads) ----
__device__ __forceinline__ void poll_all256(const unsigned* a, unsigned e) {
    const int i0 = (int)(threadIdx.x & 63) * 4;
    for (;;) {
        bool ok = (__hip_atomic_load(a + i0 + 0, __ATOMIC_RELAXED, __HIP_MEMORY_SCOPE_AGENT) >= e) &&
                  (__hip_atomic_load(a + i0 + 1, __ATOMIC_RELAXED, __HIP_MEMORY_SCOPE_AGENT) >= e) &&
                  (__hip_atomic_load(a + i0 + 2, __ATOMIC_RELAXED, __HIP_MEMORY_SCOPE_AGENT) >= e) &&
                  (__hip_atomic_load(a + i0 + 3, __ATOMIC_RELAXED, __HIP_MEMORY_SCOPE_AGENT) >= e);
        if (__all(ok)) break;
        __builtin_amdgcn_s_sleep(1);
    }
}
__device__ __forceinline__ void poll_proj(const unsigned* a2, unsigned e) {
    const int l = (int)(threadIdx.x & 63);
    for (;;) {
        bool ok = (l >= NPROJ) ||
                  (__hip_atomic_load(a2 + l, __ATOMIC_RELAXED, __HIP_MEMORY_SCOPE_AGENT) >= e);
        if (__all(ok)) break;
        __builtin_amdgcn_s_sleep(1);
    }
}

// ---------- precompute: transpose [R][C] fp32 -> [C][R] bf16 hi/lo ----------
__global__ void transpose_split(const float* __restrict__ in,
                                unsigned short* __restrict__ outHi,
                                unsigned short* __restrict__ outLo,
                                int R, int C) {
    __shared__ float tile[32][33];
    const int c0 = blockIdx.x * 32;
    const int r0 = blockIdx.y * 32;
    const int tid = threadIdx.x;  // 256
    {
        int r = tid >> 3, q = (tid & 7) * 4;
        const float* p = in + (size_t)(r0 + r) * C + c0 + q;
        float4 v = *(const float4*)p;
        tile[q + 0][r] = v.x; tile[q + 1][r] = v.y;
        tile[q + 2][r] = v.z; tile[q + 3][r] = v.w;
    }
    __syncthreads();
    {
        int c = tid >> 3, q = (tid & 7) * 4;
        ushort4 h, l;
        unsigned short hh, ll;
        split2(tile[c][q + 0], hh, ll); h.x = hh; l.x = ll;
        split2(tile[c][q + 1], hh, ll); h.y = hh; l.y = ll;
        split2(tile[c][q + 2], hh, ll); h.z = hh; l.z = ll;
        split2(tile[c][q + 3], hh, ll); h.w = hh; l.w = ll;
        size_t o = (size_t)(c0 + c) * R + r0 + q;
        *(ushort4*)(outHi + o) = h;
        *(ushort4*)(outLo + o) = l;
    }
}

// ---------- main persistent kernel ----------
__global__ void __launch_bounds__(NTHR, 2) lstm_mfma(
    const float* __restrict__ x,
    const float* __restrict__ bias0, const float* __restrict__ bias1,
    const unsigned short* __restrict__ WH0, const unsigned short* __restrict__ WL0,
    const unsigned short* __restrict__ WH1, const unsigned short* __restrict__ WL1,
    const unsigned short* __restrict__ PH0, const unsigned short* __restrict__ PL0,
    const unsigned short* __restrict__ PH1, const unsigned short* __restrict__ PL1,
    float* __restrict__ hbuf,              // [32][2048] fp32
    float* __restrict__ mb0, float* __restrict__ mb1,  // [32][640] fp32
    float* out, unsigned* arr1, unsigned* arr2) {
    __shared__ float part[8][64][20];
    __shared__ float zb[32][33];

    const int tid = threadIdx.x, bid = blockIdx.x;
    const int wid = tid >> 6, lane = tid & 63;
    const int n = lane & 31, kg = lane >> 5;
    unsigned e1 = 0, e2 = 0;

    const int col = (n >> 3) * 2048 + bid * 8 + (n & 7);
    const size_t wOffX = (size_t)col * 1280 + wid * 80 + kg * 8;
    const size_t wOffM = wOffX + 640;
    const size_t aXOff = (size_t)n * (256 * 640) + wid * 80 + kg * 8;  // + t*640
    const size_t aMOff = (size_t)n * 640 + wid * 80 + kg * 8;
    const size_t hOff  = (size_t)n * 2048 + wid * 256 + kg * 8;
    const size_t pOff  = ((size_t)(bid * 32 + n)) * 2048 + wid * 256 + kg * 8;

    // reduce mapping: D col=lane&31, row=(reg&3)+8*(reg>>2)+4*(lane>>5)
    const int rn  = tid >> 4;
    const int rm0 = (tid & 15) * 2;
    const int ch = tid >> 5, cb = tid & 31;  // cell mapping (tid<256)

    for (int layer = 0; layer < 2; ++layer) {
        const bool l0 = (layer == 0);
        const unsigned short* WH = l0 ? WH0 : WH1;
        const unsigned short* WL = l0 ? WL0 : WL1;
        const unsigned short* PH = l0 ? PH0 : PH1;
        const unsigned short* PL = l0 ? PL0 : PL1;
        const float* bb = l0 ? bias0 : bias1;
        const float bv = bb[(rn >> 3) * 2048 + bid * 8 + (rn & 7)];

        // ---- hoist this block's entire gate-weight slice into registers ----
        s16x8 wxh[5], wxl[5], wmh[5], wml[5];
        #pragma unroll
        for (int ks = 0; ks < 5; ++ks) {
            wxh[ks] = *(const s16x8*)(WH + wOffX + ks * 16);
            wxl[ks] = *(const s16x8*)(WL + wOffX + ks * 16);
            wmh[ks] = *(const s16x8*)(WH + wOffM + ks * 16);
            wml[ks] = *(const s16x8*)(WL + wOffM + ks * 16);
        }

        // zero m0 (initial recurrent state), agent stores
        for (int i = bid * NTHR + tid; i < 32 * 640; i += NBLK * NTHR) ast32(mb0 + i, 0.f);
        float creg = 0.f;

        // full barrier: m0 zeros + (layer1) complete `out` visible
        {
            __syncthreads();
            const unsigned e = ++e1;
            if (tid == 0)
                __hip_atomic_store(arr1 + bid, e, __ATOMIC_RELEASE, __HIP_MEMORY_SCOPE_AGENT);
            if (tid < 64) poll_all256(arr1, e);
            __syncthreads();
        }

        // x-part for t=0 (layer0: cached x reads; layer1: agent reads of out)
        f32x16 zacc;
        {
            #pragma unroll
            for (int r = 0; r < 16; ++r) zacc[r] = 0.f;
            const float* xb = l0 ? (x + aXOff) : ((const float*)out + aXOff);
            #pragma unroll
            for (int ks = 0; ks < 5; ++ks) {
                float f[8];
                if (l0) {
                    float4 v0 = *(const float4*)(xb + ks * 16);
                    float4 v1 = *(const float4*)(xb + ks * 16 + 4);
                    f[0] = v0.x; f[1] = v0.y; f[2] = v0.z; f[3] = v0.w;
                    f[4] = v1.x; f[5] = v1.y; f[6] = v1.z; f[7] = v1.w;
                } else {
                    ld8f(xb + ks * 16, f);
                }
                s16x8 ah, al;
                split8(f, ah, al);
                zacc = __builtin_amdgcn_mfma_f32_32x32x16_bf16(ah, wxh[ks], zacc, 0, 0, 0);
                zacc = __builtin_amdgcn_mfma_f32_32x32x16_bf16(ah, wxl[ks], zacc, 0, 0, 0);
                zacc = __builtin_amdgcn_mfma_f32_32x32x16_bf16(al, wxh[ks], zacc, 0, 0, 0);
            }
        }

        for (int t = 0; t < 256; ++t) {
            const float* mcur = (t & 1) ? mb1 : mb0;
            float* mnxt = (t & 1) ? mb0 : mb1;

            // ===== phase A: z = carried x-part + m(t)·Wm (weights in VGPRs) =====
            f32x16 acc = zacc;
            {
                const float* mrow = mcur + aMOff;
                #pragma unroll
                for (int ks = 0; ks < 5; ++ks) {
                    float f[8];
                    ld8f(mrow + ks * 16, f);
                    s16x8 ah, al;
                    split8(f, ah, al);
                    acc = __builtin_amdgcn_mfma_f32_32x32x16_bf16(ah, wmh[ks], acc, 0, 0, 0);
                    acc = __builtin_amdgcn_mfma_f32_32x32x16_bf16(ah, wml[ks], acc, 0, 0, 0);
                    acc = __builtin_amdgcn_mfma_f32_32x32x16_bf16(al, wmh[ks], acc, 0, 0, 0);
                }
            }
            #pragma unroll
            for (int r = 0; r < 4; r++) {
                float4 v;
                v.x = acc[4 * r + 0]; v.y = acc[4 * r + 1];
                v.z = acc[4 * r + 2]; v.w = acc[4 * r + 3];
                *(float4*)&part[wid][lane][4 * r] = v;
            }
            __syncthreads();
            #pragma unroll
            for (int j = 0; j < 2; j++) {
                int m = rm0 + j;
                int lp = rn + 32 * ((m >> 2) & 1);
                int rg = (m & 3) + 4 * (m >> 3);
                float s = 0.f;
                #pragma unroll
                for (int w = 0; w < 8; w++) s += part[w][lp][rg];
                zb[rn][m] = s + bv;
            }
            __syncthreads();

            // ===== cell update + h agent-store (gate order i, j, f, o) =====
            if (tid < 256) {
                float zi = zb[0 * 8 + ch][cb];
                float zj = zb[1 * 8 + ch][cb];
                float zf = zb[2 * 8 + ch][cb];
                float zo = zb[3 * 8 + ch][cb];
                float cn = sigm(zf + 1.0f) * creg + sigm(zi) * tanhf(zj);
                creg = cn;
                ast32(hbuf + (size_t)cb * 2048 + bid * 8 + ch, sigm(zo) * tanhf(cn));
            }
            __syncthreads();  // drains all waves' stores (vmcnt before s_barrier)
            const unsigned e1c = ++e1;
            if (tid == 0)
                __hip_atomic_store(arr1 + bid, e1c, __ATOMIC_RELEASE, __HIP_MEMORY_SCOPE_AGENT);
            const unsigned e2c = ++e2;

            // ===== phase B: projection (blocks 0..19 only wait on BAR1) =====
            if (bid < NPROJ) {
                if (tid < 64) poll_all256(arr1, e1c);
                __syncthreads();
                f32x16 pacc;
                #pragma unroll
                for (int r = 0; r < 16; r++) pacc[r] = 0.f;
                const float* hrow = hbuf + hOff;
                const unsigned short* php = PH + pOff;
                const unsigned short* plp = PL + pOff;
                #pragma unroll
                for (int ks = 0; ks < 16; ++ks) {
                    float f[8];
                    ld8f(hrow + ks * 16, f);
                    s16x8 ahh, alo;
                    split8(f, ahh, alo);
                    s16x8 bhh = *(const s16x8*)(php + ks * 16);
                    s16x8 blo = *(const s16x8*)(plp + ks * 16);
                    pacc = __builtin_amdgcn_mfma_f32_32x32x16_bf16(ahh, bhh, pacc, 0, 0, 0);
                    pacc = __builtin_amdgcn_mfma_f32_32x32x16_bf16(ahh, blo, pacc, 0, 0, 0);
                    pacc = __builtin_amdgcn_mfma_f32_32x32x16_bf16(alo, bhh, pacc, 0, 0, 0);
                }
                #pragma unroll
                for (int r = 0; r < 4; r++) {
                    float4 v;
                    v.x = pacc[4 * r + 0]; v.y = pacc[4 * r + 1];
                    v.z = pacc[4 * r + 2]; v.w = pacc[4 * r + 3];
                    *(float4*)&part[wid][lane][4 * r] = v;
                }
                __syncthreads();
                #pragma unroll
                for (int j = 0; j < 2; j++) {
                    int m = rm0 + j;
                    int lp = rn + 32 * ((m >> 2) & 1);
                    int rg = (m & 3) + 4 * (m >> 3);
                    float s = 0.f;
                    #pragma unroll
                    for (int w = 0; w < 8; w++) s += part[w][lp][rg];
                    int p = bid * 32 + rn;
                    ast32(out + ((size_t)m * 256 + t) * 640 + p, s);
                    ast32(mnxt + m * 640 + p, s);
                }
                __syncthreads();  // drain m/out stores
                if (tid == 0)
                    __hip_atomic_store(arr2 + bid, e2c, __ATOMIC_RELEASE, __HIP_MEMORY_SCOPE_AGENT);
            }

            // ===== x-part(t+1), overlapped with projection + propagation =====
            if (t < 255) {
                #pragma unroll
                for (int r = 0; r < 16; ++r) zacc[r] = 0.f;
                const float* xb = (l0 ? x : (const float*)out) + aXOff + (size_t)(t + 1) * 640;
                #pragma unroll
                for (int ks = 0; ks < 5; ++ks) {
                    float f[8];
                    if (l0) {
                        float4 v0 = *(const float4*)(xb + ks * 16);
                        float4 v1 = *(const float4*)(xb + ks * 16 + 4);
                        f[0] = v0.x; f[1] = v0.y; f[2] = v0.z; f[3] = v0.w;
                        f[4] = v1.x; f[5] = v1.y; f[6] = v1.z; f[7] = v1.w;
                    } else {
                        ld8f(xb + ks * 16, f);
                    }
                    s16x8 ah, al;
                    split8(f, ah, al);
                    zacc = __builtin_amdgcn_mfma_f32_32x32x16_bf16(ah, wxh[ks], zacc, 0, 0, 0);
                    zacc = __builtin_amdgcn_mfma_f32_32x32x16_bf16(ah, wxl[ks], zacc, 0, 0, 0);
                    zacc = __builtin_amdgcn_mfma_f32_32x32x16_bf16(al, wxh[ks], zacc, 0, 0, 0);
                }
            }

            // ===== BAR2: m(t+1) visible =====
            if (tid < 64) poll_proj(arr2, e2c);
            __syncthreads();
        }
    }
}

// ---------- fallback (R1-style) if ws too small ----------
__device__ __forceinline__ void grid_bar_slow(unsigned int* bar, unsigned int& epoch) {
    __syncthreads();
    epoch++;
    if (threadIdx.x == 0) {
        __threadfence();
        atomicAdd(bar, 1u);
        const unsigned int target = epoch * NBLK;
        while (__hip_atomic_load(bar, __ATOMIC_RELAXED, __HIP_MEMORY_SCOPE_AGENT) < target) {
            __builtin_amdgcn_s_sleep(1);
        }
        __threadfence();
    }
    __syncthreads();
}

__global__ void __launch_bounds__(NTHR, 1) lstm_fb(
    const float* __restrict__ x,
    const float* __restrict__ W0, const float* __restrict__ b0, const float* __restrict__ Pr0,
    const float* __restrict__ W1, const float* __restrict__ b1, const float* __restrict__ Pr1,
    float* out, float* ws) {
    const int tid = threadIdx.x;
    const int bid = blockIdx.x;
    unsigned int* bar = (unsigned int*)ws;
    float* mbuf0 = ws + 1024;
    float* mbuf1 = mbuf0 + 32 * 640;
    float* hws = mbuf1 + 32 * 640;
    __shared__ float zbuf[32 * 33];
    __shared__ float pred[512];
    unsigned int epoch = 0;
    const int c_idx = tid & 31;
    const int bg = tid >> 5;
    const int b0r = bg * 2;
    const int col = (c_idx >> 3) * 2048 + bid * 8 + (c_idx & 7);
    const int ch = tid >> 5;
    const int cb = tid & 31;
    const int p_s = (bid * 640) / NBLK;
    const int p_e = ((bid + 1) * 640) / NBLK;
    const int np = p_e - p_s;
    const int kq_n = (np == 2) ? 8 : 4;
    const int klen = 2048 / kq_n;
    const int pg = tid >> 5;
    const bool pact = pg < np * kq_n;
    const int pj = pact ? (pg % np) : 0;
    const int kq = pact ? (pg / np) : 0;
    for (int layer = 0; layer < 2; ++layer) {
        const float* W = layer ? W1 : W0;
        const float* bbv = layer ? b1 : b0;
        const float* Pr = layer ? Pr1 : Pr0;
        const float* inb = layer ? (const float*)out : x;
        for (int i = bid * NTHR + tid; i < 32 * 640; i += NBLK * NTHR) mbuf0[i] = 0.0f;
        float creg = 0.0f;
        grid_bar_slow(bar, epoch);
        const float bias = bbv[col];
        for (int t = 0; t < 256; ++t) {
            float* mcur = (t & 1) ? mbuf1 : mbuf0;
            float* mnxt = (t & 1) ? mbuf0 : mbuf1;
            const float* in0 = inb + (size_t)(b0r * 256 + t) * 640;
            const float* in1 = in0 + (size_t)256 * 640;
            const float* wp = W + col;
            float a0 = 0.f, a1 = 0.f;
            #pragma unroll 4
            for (int k = 0; k < 640; k += 4) {
                float4 u0 = *(const float4*)(in0 + k);
                float4 u1 = *(const float4*)(in1 + k);
                float w0 = wp[(size_t)(k + 0) * 8192], w1 = wp[(size_t)(k + 1) * 8192];
                float w2 = wp[(size_t)(k + 2) * 8192], w3 = wp[(size_t)(k + 3) * 8192];
                a0 += w0 * u0.x + w1 * u0.y + w2 * u0.z + w3 * u0.w;
                a1 += w0 * u1.x + w1 * u1.y + w2 * u1.z + w3 * u1.w;
            }
            const float* q0 = mcur + (size_t)b0r * 640;
            const float* q1 = q0 + 640;
            #pragma unroll 4
            for (int k = 0; k < 640; k += 4) {
                float4 u0 = *(const float4*)(q0 + k);
                float4 u1 = *(const float4*)(q1 + k);
                float w0 = wp[(size_t)(640 + k + 0) * 8192], w1 = wp[(size_t)(640 + k + 1) * 8192];
                float w2 = wp[(size_t)(640 + k + 2) * 8192], w3 = wp[(size_t)(640 + k + 3) * 8192];
                a0 += w0 * u0.x + w1 * u0.y + w2 * u0.z + w3 * u0.w;
                a1 += w0 * u1.x + w1 * u1.y + w2 * u1.z + w3 * u1.w;
            }
            zbuf[c_idx * 33 + b0r + 0] = a0 + bias;
            zbuf[c_idx * 33 + b0r + 1] = a1 + bias;
            __syncthreads();
            if (tid < 256) {
                float zi = zbuf[(0 * 8 + ch) * 33 + cb];
                float zj = zbuf[(1 * 8 + ch) * 33 + cb];
                float zf = zbuf[(2 * 8 + ch) * 33 + cb];
                float zo = zbuf[(3 * 8 + ch) * 33 + cb];
                float cn = sigm(zf + 1.0f) * creg + sigm(zi) * tanhf(zj);
                creg = cn;
                hws[(size_t)(bid * 8 + ch) * 32 + cb] = sigm(zo) * tanhf(cn);
            }
            grid_bar_slow(bar, epoch);
            if (pact) {
                const int p = p_s + pj;
                const float* pp = Pr + p;
                const int k0 = kq * klen;
                float s = 0.f;
                #pragma unroll 4
                for (int k = k0; k < k0 + klen; ++k) s += hws[(size_t)k * 32 + cb] * pp[(size_t)k * 640];
                pred[(pj * 32 + cb) * kq_n + kq] = s;
            }
            __syncthreads();
            if (tid < np * 32) {
                float s = 0.f;
                for (int q2 = 0; q2 < kq_n; ++q2) s += pred[tid * kq_n + q2];
                const int p = p_s + (tid >> 5);
                const int b = tid & 31;
                mnxt[(size_t)b * 640 + p] = s;
                out[((size_t)b * 256 + t) * 640 + p] = s;
            }
            grid_bar_slow(bar, epoch);
        }
    }
}

extern "C" void kernel_launch(void* const* d_in, const int* in_sizes, int n_in,
                              void* d_out, int out_size, void* d_ws, size_t ws_size,
                              hipStream_t stream) {
    const float* x   = (const float*)d_in[0];
    const float* W0  = (const float*)d_in[1];
    const float* b0  = (const float*)d_in[2];
    const float* P0  = (const float*)d_in[3];
    const float* W1  = (const float*)d_in[4];
    const float* b1  = (const float*)d_in[5];
    const float* P1  = (const float*)d_in[6];
    float* out = (float*)d_out;

    // ws layout (bytes, 256-aligned chunks)
    size_t off = 0;
    auto alloc = [&](size_t bytes) { size_t o = off; off += (bytes + 255) & ~(size_t)255; return o; };
    const size_t oBar = alloc(4096);              // arr1[256] @0, arr2[..] @2048
    const size_t szW = (size_t)8192 * 1280 * 2;   // bf16 [8192][1280]
    const size_t szP = (size_t)640 * 2048 * 2;    // bf16 [640][2048]
    const size_t oWH0 = alloc(szW), oWL0 = alloc(szW), oWH1 = alloc(szW), oWL1 = alloc(szW);
    const size_t oPH0 = alloc(szP), oPL0 = alloc(szP), oPH1 = alloc(szP), oPL1 = alloc(szP);
    const size_t oH  = alloc((size_t)32 * 2048 * 4);   // h fp32
    const size_t oM0 = alloc((size_t)32 * 640 * 4);    // m fp32 double buffer
    const size_t oM1 = alloc((size_t)32 * 640 * 4);
    const size_t need = off;

    hipMemsetAsync(d_ws, 0, 4096, stream);  // barrier flags must start at 0 every call

    if (ws_size < need) {  // fallback path (~0.5 MB ws)
        float* ws = (float*)d_ws;
        void* args[] = {(void*)&x, (void*)&W0, (void*)&b0, (void*)&P0,
                        (void*)&W1, (void*)&b1, (void*)&P1, (void*)&out, (void*)&ws};
        hipError_t e = hipLaunchCooperativeKernel((const void*)lstm_fb,
                                                  dim3(NBLK), dim3(NTHR), args, 0, stream);
        if (e != hipSuccess)
            lstm_fb<<<dim3(NBLK), dim3(NTHR), 0, stream>>>(x, W0, b0, P0, W1, b1, P1, out, ws);
        return;
    }

    char* w = (char*)d_ws;
    unsigned short *WH0p = (unsigned short*)(w + oWH0), *WL0p = (unsigned short*)(w + oWL0);
    unsigned short *WH1p = (unsigned short*)(w + oWH1), *WL1p = (unsigned short*)(w + oWL1);
    unsigned short *PH0p = (unsigned short*)(w + oPH0), *PL0p = (unsigned short*)(w + oPL0);
    unsigned short *PH1p = (unsigned short*)(w + oPH1), *PL1p = (unsigned short*)(w + oPL1);
    float* hp  = (float*)(w + oH);
    float* m0p = (float*)(w + oM0);
    float* m1p = (float*)(w + oM1);
    unsigned *arr1p = (unsigned*)(w + oBar);
    unsigned *arr2p = (unsigned*)(w + oBar + 2048);

    // precompute: transpose+split weights
    transpose_split<<<dim3(8192 / 32, 1280 / 32), 256, 0, stream>>>(W0, WH0p, WL0p, 1280, 8192);
    transpose_split<<<dim3(8192 / 32, 1280 / 32), 256, 0, stream>>>(W1, WH1p, WL1p, 1280, 8192);
    transpose_split<<<dim3(640 / 32, 2048 / 32), 256, 0, stream>>>(P0, PH0p, PL0p, 2048, 640);
    transpose_split<<<dim3(640 / 32, 2048 / 32), 256, 0, stream>>>(P1, PH1p, PL1p, 2048, 640);

    const float *b0c = b0, *b1c = b1;
    void* args[] = {(void*)&x, (void*)&b0c, (void*)&b1c,
                    (void*)&WH0p, (void*)&WL0p, (void*)&WH1p, (void*)&WL1p,
                    (void*)&PH0p, (void*)&PL0p, (void*)&PH1p, (void*)&PL1p,
                    (void*)&hp, (void*)&m0p, (void*)&m1p,
                    (void*)&out, (void*)&arr1p, (void*)&arr2p};
    hipError_t e = hipLaunchCooperativeKernel((const void*)lstm_mfma,
                                              dim3(NBLK), dim3(NTHR), args, 0, stream);
    if (e != hipSuccess)
        lstm_mfma<<<dim3(NBLK), dim3(NTHR), 0, stream>>>(
            x, b0c, b1c, WH0p, WL0p, WH1p, WL1p, PH0p, PL0p, PH1p, PL1p,
            hp, m0p, m1p, out, arr1p, arr2p);
}

// Round 5
// 11441.445 us; speedup vs baseline: 7.2744x; 1.8590x over previous
//
#include <hip/hip_runtime.h>
#include <math.h>

typedef __attribute__((ext_vector_type(8))) short s16x8;
typedef __attribute__((ext_vector_type(8))) _Float16 f16x8;
typedef __attribute__((ext_vector_type(16))) float f32x16;
typedef unsigned long long u64;
typedef unsigned short u16;

#define NBLK 256
#define NTHR 512

constexpr int HSZ = 32 * 2048;  // one h buffer, f16 elems

__device__ __forceinline__ float sigm(float v) { return 1.0f / (1.0f + expf(-v)); }

__device__ __forceinline__ unsigned short bf16_rne(float x) {
    unsigned u = __float_as_uint(x);
    return (unsigned short)((u + 0x7FFFu + ((u >> 16) & 1u)) >> 16);
}
__device__ __forceinline__ void split2(float x, unsigned short& hi, unsigned short& lo) {
    unsigned u = __float_as_uint(x);
    hi = (unsigned short)(u >> 16);
    float hf = __uint_as_float(u & 0xFFFF0000u);
    lo = bf16_rne(x - hf);
}
__device__ __forceinline__ void split8(const float* f, s16x8& h, s16x8& l) {
    #pragma unroll
    for (int i = 0; i < 8; ++i) {
        unsigned short hh, ll;
        split2(f[i], hh, ll);
        h[i] = (short)hh; l[i] = (short)ll;
    }
}

// ---- agent-scope (L3 coherence point) accessors for cross-block data ----
__device__ __forceinline__ u64 ald64(const void* p) {
    return __hip_atomic_load((const u64*)p, __ATOMIC_RELAXED, __HIP_MEMORY_SCOPE_AGENT);
}
__device__ __forceinline__ void ast64(u16* p, u64 v) {
    __hip_atomic_store((u64*)p, v, __ATOMIC_RELAXED, __HIP_MEMORY_SCOPE_AGENT);
}
__device__ __forceinline__ void ast32(float* p, float v) {
    __hip_atomic_store((unsigned*)p, __float_as_uint(v), __ATOMIC_RELAXED, __HIP_MEMORY_SCOPE_AGENT);
}
__device__ __forceinline__ f16x8 ald_f16x8(const u16* p) {
    union { u64 q[2]; f16x8 v; } u;
    u.q[0] = ald64(p);
    u.q[1] = ald64(p + 4);
    return u.v;
}

// ---- single-flag-array barrier pieces ----
__device__ __forceinline__ void arrive(unsigned* arr, unsigned e) {
    __syncthreads();  // drains each thread's stores (vmcnt before s_barrier)
    if (threadIdx.x == 0)
        __hip_atomic_store(arr + blockIdx.x, e, __ATOMIC_RELEASE, __HIP_MEMORY_SCOPE_AGENT);
}
__device__ __forceinline__ void pollall(const unsigned* arr, unsigned e) {
    if (threadIdx.x < 64) {
        const int i0 = (int)threadIdx.x * 4;
        for (;;) {
            bool ok = (__hip_atomic_load(arr + i0 + 0, __ATOMIC_RELAXED, __HIP_MEMORY_SCOPE_AGENT) >= e) &&
                      (__hip_atomic_load(arr + i0 + 1, __ATOMIC_RELAXED, __HIP_MEMORY_SCOPE_AGENT) >= e) &&
                      (__hip_atomic_load(arr + i0 + 2, __ATOMIC_RELAXED, __HIP_MEMORY_SCOPE_AGENT) >= e) &&
                      (__hip_atomic_load(arr + i0 + 3, __ATOMIC_RELAXED, __HIP_MEMORY_SCOPE_AGENT) >= e);
            if (__all(ok)) break;
            __builtin_amdgcn_s_sleep(1);
        }
    }
    __syncthreads();
}

// ---------- precompute: transpose [R][C] fp32 -> [C][R] bf16 hi/lo ----------
__global__ void transpose_split(const float* __restrict__ in,
                                u16* __restrict__ outHi, u16* __restrict__ outLo,
                                int R, int C) {
    __shared__ float tile[32][33];
    const int c0 = blockIdx.x * 32, r0 = blockIdx.y * 32;
    const int tid = threadIdx.x;  // 256
    {
        int r = tid >> 3, q = (tid & 7) * 4;
        float4 v = *(const float4*)(in + (size_t)(r0 + r) * C + c0 + q);
        tile[q + 0][r] = v.x; tile[q + 1][r] = v.y;
        tile[q + 2][r] = v.z; tile[q + 3][r] = v.w;
    }
    __syncthreads();
    {
        int c = tid >> 3, q = (tid & 7) * 4;
        ushort4 h, l;
        unsigned short hh, ll;
        split2(tile[c][q + 0], hh, ll); h.x = hh; l.x = ll;
        split2(tile[c][q + 1], hh, ll); h.y = hh; l.y = ll;
        split2(tile[c][q + 2], hh, ll); h.z = hh; l.z = ll;
        split2(tile[c][q + 3], hh, ll); h.w = hh; l.w = ll;
        size_t o = (size_t)(c0 + c) * R + r0 + q;
        *(ushort4*)(outHi + o) = h;
        *(ushort4*)(outLo + o) = l;
    }
}

// ---------- precompute: transpose [R][C] fp32 -> [C][R] f16 ----------
__global__ void transpose_f16(const float* __restrict__ in, u16* __restrict__ outp,
                              int R, int C) {
    __shared__ float tile[32][33];
    const int c0 = blockIdx.x * 32, r0 = blockIdx.y * 32;
    const int tid = threadIdx.x;  // 256
    {
        int r = tid >> 3, q = (tid & 7) * 4;
        float4 v = *(const float4*)(in + (size_t)(r0 + r) * C + c0 + q);
        tile[q + 0][r] = v.x; tile[q + 1][r] = v.y;
        tile[q + 2][r] = v.z; tile[q + 3][r] = v.w;
    }
    __syncthreads();
    {
        int c = tid >> 3, q = (tid & 7) * 4;
        ushort4 o;
        o.x = __builtin_bit_cast(u16, (_Float16)tile[c][q + 0]);
        o.y = __builtin_bit_cast(u16, (_Float16)tile[c][q + 1]);
        o.z = __builtin_bit_cast(u16, (_Float16)tile[c][q + 2]);
        o.w = __builtin_bit_cast(u16, (_Float16)tile[c][q + 3]);
        *(ushort4*)(outp + (size_t)(c0 + c) * R + r0 + q) = o;
    }
}

// ---------- precompute: Qt[8192][2048] f16 = (P[2048][640] @ Wm[640][8192])^T ----------
// B-operand comes from the already-transposed Wt (rows 640..1279 = Wm^T).
__global__ void __launch_bounds__(256) qgemm(const float* __restrict__ P,
    const u16* __restrict__ WH, const u16* __restrict__ WL,
    u16* __restrict__ Qt) {
    const int tid = threadIdx.x;
    const int wid = tid >> 6, lane = tid & 63;
    const int n = lane & 31, kg = lane >> 5;
    const int tile = blockIdx.x * 4 + wid;   // 0..16383
    const int ct = tile & 255, kt = tile >> 8;
    const int col = ct * 32 + n;
    const int krow = kt * 32 + n;

    f32x16 acc;
    #pragma unroll
    for (int r = 0; r < 16; ++r) acc[r] = 0.f;

    const float* ap = P + (size_t)krow * 640 + kg * 8;
    const u16* bhp = WH + (size_t)col * 1280 + 640 + kg * 8;
    const u16* blp = WL + (size_t)col * 1280 + 640 + kg * 8;
    #pragma unroll 4
    for (int ks = 0; ks < 40; ++ks) {
        float4 v0 = *(const float4*)(ap + ks * 16);
        float4 v1 = *(const float4*)(ap + ks * 16 + 4);
        float f[8] = {v0.x, v0.y, v0.z, v0.w, v1.x, v1.y, v1.z, v1.w};
        s16x8 ah, al;
        split8(f, ah, al);
        s16x8 bh = *(const s16x8*)(bhp + ks * 16);
        s16x8 bl = *(const s16x8*)(blp + ks * 16);
        acc = __builtin_amdgcn_mfma_f32_32x32x16_bf16(ah, bh, acc, 0, 0, 0);
        acc = __builtin_amdgcn_mfma_f32_32x32x16_bf16(ah, bl, acc, 0, 0, 0);
        acc = __builtin_amdgcn_mfma_f32_32x32x16_bf16(al, bh, acc, 0, 0, 0);
    }
    // D row = (reg&3) + 8*(reg>>2) + 4*kg; store transposed: Qt[col][kt*32 + row]
    u16* qrow = Qt + (size_t)col * 2048 + kt * 32 + 4 * kg;
    #pragma unroll
    for (int q = 0; q < 4; ++q) {
        ushort4 o;
        o.x = __builtin_bit_cast(u16, (_Float16)acc[4 * q + 0]);
        o.y = __builtin_bit_cast(u16, (_Float16)acc[4 * q + 1]);
        o.z = __builtin_bit_cast(u16, (_Float16)acc[4 * q + 2]);
        o.w = __builtin_bit_cast(u16, (_Float16)acc[4 * q + 3]);
        *(ushort4*)(qrow + 8 * q) = o;
    }
}

// ---------- main persistent kernel: one handoff per step ----------
__global__ void __launch_bounds__(NTHR, 2) lstm_q(
    const float* __restrict__ x,
    const float* __restrict__ bias0, const float* __restrict__ bias1,
    const u16* __restrict__ WH0, const u16* __restrict__ WL0,
    const u16* __restrict__ WH1, const u16* __restrict__ WL1,
    const u16* __restrict__ Qt0, const u16* __restrict__ Qt1,
    const u16* __restrict__ Pt0, const u16* __restrict__ Pt1,
    u16* __restrict__ hb,      // [3][32][2048] f16
    float* out, unsigned* arr) {
    __shared__ float part[8][64][20];
    __shared__ float zb[32][33];
    __shared__ u16 hst[32][8];

    const int tid = threadIdx.x, bid = blockIdx.x;
    const int wid = tid >> 6, lane = tid & 63;
    const int n = lane & 31, kg = lane >> 5;
    unsigned e = 0;

    const int colmap = (n >> 3) * 2048 + bid * 8 + (n & 7);
    const size_t wOffX = (size_t)colmap * 1280 + wid * 80 + kg * 8;   // Wx k-slice
    const size_t qOff  = (size_t)colmap * 2048 + wid * 256 + kg * 8;  // Qt slice
    const size_t aXOff = (size_t)n * (256 * 640) + wid * 80 + kg * 8; // + t*640
    const size_t hROff = (size_t)n * 2048 + wid * 256 + kg * 8;       // h frag base

    // reduce mapping: D col=lane&31, row=(reg&3)+8*(reg>>2)+4*(lane>>5)
    const int rn = tid >> 4, rm0 = (tid & 15) * 2;
    const int ch = tid >> 5, cb = tid & 31;   // cell mapping (tid<256)

    const bool isTeam = bid < 40;
    const int tb = (bid < 20) ? bid : bid - 20;
    const int myPar = (bid < 20) ? 0 : 1;
    const size_t pOff = (size_t)(tb * 32 + n) * 2048 + wid * 256 + kg * 8;

    for (int layer = 0; layer < 2; ++layer) {
        const bool l0 = (layer == 0);
        const u16* WH = l0 ? WH0 : WH1;
        const u16* WL = l0 ? WL0 : WL1;
        const u16* Qt = l0 ? Qt0 : Qt1;
        const u16* Pt = l0 ? Pt0 : Pt1;
        const float bv = (l0 ? bias0 : bias1)[(rn >> 3) * 2048 + bid * 8 + (rn & 7)];
        const float* inp = l0 ? x : (const float*)out;  // plain loads (fresh: first touch after write)

        // Q fragments register-resident for the whole layer (64 VGPRs)
        f16x8 qf[16];
        #pragma unroll
        for (int ks = 0; ks < 16; ++ks) qf[ks] = *(const f16x8*)(Qt + qOff + ks * 16);

        float creg = 0.f;

        // layer-entry barrier (layer 1: gates on all of layer 0's out)
        ++e; arrive(arr, e); pollall(arr, e);

        // x-part of z(t) carried in registers, computed one step ahead
        auto xpart = [&](int t) -> f32x16 {
            f32x16 a;
            #pragma unroll
            for (int r = 0; r < 16; ++r) a[r] = 0.f;
            const float* xb = inp + aXOff + (size_t)t * 640;
            const u16* whx = WH + wOffX;
            const u16* wlx = WL + wOffX;
            #pragma unroll
            for (int ks = 0; ks < 5; ++ks) {
                float4 v0 = *(const float4*)(xb + ks * 16);
                float4 v1 = *(const float4*)(xb + ks * 16 + 4);
                float f[8] = {v0.x, v0.y, v0.z, v0.w, v1.x, v1.y, v1.z, v1.w};
                s16x8 ah, al;
                split8(f, ah, al);
                s16x8 bh = *(const s16x8*)(whx + ks * 16);
                s16x8 bl = *(const s16x8*)(wlx + ks * 16);
                a = __builtin_amdgcn_mfma_f32_32x32x16_bf16(ah, bh, a, 0, 0, 0);
                a = __builtin_amdgcn_mfma_f32_32x32x16_bf16(ah, bl, a, 0, 0, 0);
                a = __builtin_amdgcn_mfma_f32_32x32x16_bf16(al, bh, a, 0, 0, 0);
            }
            return a;
        };

        // proj epilogue: reduce pacc across waves, write out[., tp, .] (agent stores)
        auto projout = [&](int tp, f32x16 pacc) {
            __syncthreads();
            #pragma unroll
            for (int r = 0; r < 4; r++) {
                float4 v;
                v.x = pacc[4 * r + 0]; v.y = pacc[4 * r + 1];
                v.z = pacc[4 * r + 2]; v.w = pacc[4 * r + 3];
                *(float4*)&part[wid][lane][4 * r] = v;
            }
            __syncthreads();
            #pragma unroll
            for (int j = 0; j < 2; j++) {
                int m = rm0 + j;
                int lp = rn + 32 * ((m >> 2) & 1);
                int rg = (m & 3) + 4 * (m >> 3);
                float s = 0.f;
                #pragma unroll
                for (int w = 0; w < 8; w++) s += part[w][lp][rg];
                ast32(out + ((size_t)m * 256 + tp) * 640 + tb * 32 + rn, s);
            }
        };

        f32x16 zacc = xpart(0);

        for (int t = 0; t < 256; ++t) {
            if (t > 0) pollall(arr, e);   // h(t-1) slices all published

            const bool doProj = isTeam && (t > 0) && (((t - 1) & 1) == myPar);
            f32x16 acc = zacc;
            f32x16 pacc;
            if (t > 0) {
                const u16* hc = hb + (size_t)((t + 2) % 3) * HSZ + hROff;  // buf (t-1)%3
                if (doProj) {
                    #pragma unroll
                    for (int r = 0; r < 16; ++r) pacc[r] = 0.f;
                    #pragma unroll
                    for (int ks = 0; ks < 16; ++ks) {
                        f16x8 a = ald_f16x8(hc + ks * 16);  // shared by Q-GEMM and proj
                        acc  = __builtin_amdgcn_mfma_f32_32x32x16_f16(a, qf[ks], acc, 0, 0, 0);
                        f16x8 pb = *(const f16x8*)(Pt + pOff + ks * 16);
                        pacc = __builtin_amdgcn_mfma_f32_32x32x16_f16(a, pb, pacc, 0, 0, 0);
                    }
                } else {
                    #pragma unroll
                    for (int ks = 0; ks < 16; ++ks)
                        acc = __builtin_amdgcn_mfma_f32_32x32x16_f16(ald_f16x8(hc + ks * 16), qf[ks], acc, 0, 0, 0);
                }
            }

            // cross-wave K reduce -> z
            #pragma unroll
            for (int r = 0; r < 4; r++) {
                float4 v;
                v.x = acc[4 * r + 0]; v.y = acc[4 * r + 1];
                v.z = acc[4 * r + 2]; v.w = acc[4 * r + 3];
                *(float4*)&part[wid][lane][4 * r] = v;
            }
            __syncthreads();
            #pragma unroll
            for (int j = 0; j < 2; j++) {
                int m = rm0 + j;
                int lp = rn + 32 * ((m >> 2) & 1);
                int rg = (m & 3) + 4 * (m >> 3);
                float s = 0.f;
                #pragma unroll
                for (int w = 0; w < 8; w++) s += part[w][lp][rg];
                zb[rn][m] = s + bv;
            }
            __syncthreads();

            // cell update (gate order i, j, f, o); h -> LDS stage as f16
            if (tid < 256) {
                float zi = zb[0 * 8 + ch][cb];
                float zj = zb[1 * 8 + ch][cb];
                float zf = zb[2 * 8 + ch][cb];
                float zo = zb[3 * 8 + ch][cb];
                float cn = sigm(zf + 1.0f) * creg + sigm(zi) * tanhf(zj);
                creg = cn;
                float hv = sigm(zo) * tanhf(cn);
                hst[cb][ch] = __builtin_bit_cast(u16, (_Float16)hv);
            }
            __syncthreads();
            if (tid < 64) {  // publish this block's h slice: 64 x 8B agent stores
                int b = tid >> 1, hf = tid & 1;
                u64 v = *(const u64*)&hst[b][hf * 4];
                ast64(hb + (size_t)(t % 3) * HSZ + (size_t)b * 2048 + bid * 8 + hf * 4, v);
            }
            ++e; arrive(arr, e);          // h(t) published

            if (doProj) projout(t - 1, pacc);   // lagging, off critical path
            if (t < 255) zacc = xpart(t + 1);   // overlapped with others' arrival
        }

        // finish proj(255) (odd -> team B), then layer boundary
        pollall(arr, e);
        if (isTeam && myPar == 1) {
            const u16* hc = hb + (size_t)(255 % 3) * HSZ + hROff;
            f32x16 pacc;
            #pragma unroll
            for (int r = 0; r < 16; ++r) pacc[r] = 0.f;
            #pragma unroll
            for (int ks = 0; ks < 16; ++ks) {
                f16x8 a = ald_f16x8(hc + ks * 16);
                f16x8 pb = *(const f16x8*)(Pt + pOff + ks * 16);
                pacc = __builtin_amdgcn_mfma_f32_32x32x16_f16(a, pb, pacc, 0, 0, 0);
            }
            projout(255, pacc);
        }
        ++e; arrive(arr, e); pollall(arr, e);
    }
}

// ---------- fallback (R1-style) if ws too small ----------
__device__ __forceinline__ void grid_bar_slow(unsigned int* bar, unsigned int& epoch) {
    __syncthreads();
    epoch++;
    if (threadIdx.x == 0) {
        __threadfence();
        atomicAdd(bar, 1u);
        const unsigned int target = epoch * NBLK;
        while (__hip_atomic_load(bar, __ATOMIC_RELAXED, __HIP_MEMORY_SCOPE_AGENT) < target)
            __builtin_amdgcn_s_sleep(1);
        __threadfence();
    }
    __syncthreads();
}

__global__ void __launch_bounds__(NTHR, 1) lstm_fb(
    const float* __restrict__ x,
    const float* __restrict__ W0, const float* __restrict__ b0, const float* __restrict__ Pr0,
    const float* __restrict__ W1, const float* __restrict__ b1, const float* __restrict__ Pr1,
    float* out, float* ws) {
    const int tid = threadIdx.x;
    const int bid = blockIdx.x;
    unsigned int* bar = (unsigned int*)ws;
    float* mbuf0 = ws + 1024;
    float* mbuf1 = mbuf0 + 32 * 640;
    float* hws = mbuf1 + 32 * 640;
    __shared__ float zbuf[32 * 33];
    __shared__ float pred[512];
    unsigned int epoch = 0;
    const int c_idx = tid & 31;
    const int bg = tid >> 5;
    const int b0r = bg * 2;
    const int col = (c_idx >> 3) * 2048 + bid * 8 + (c_idx & 7);
    const int ch = tid >> 5;
    const int cb = tid & 31;
    const int p_s = (bid * 640) / NBLK;
    const int p_e = ((bid + 1) * 640) / NBLK;
    const int np = p_e - p_s;
    const int kq_n = (np == 2) ? 8 : 4;
    const int klen = 2048 / kq_n;
    const int pg = tid >> 5;
    const bool pact = pg < np * kq_n;
    const int pj = pact ? (pg % np) : 0;
    const int kq = pact ? (pg / np) : 0;
    for (int layer = 0; layer < 2; ++layer) {
        const float* W = layer ? W1 : W0;
        const float* bbv = layer ? b1 : b0;
        const float* Pr = layer ? Pr1 : Pr0;
        const float* inb = layer ? (const float*)out : x;
        for (int i = bid * NTHR + tid; i < 32 * 640; i += NBLK * NTHR) mbuf0[i] = 0.0f;
        float creg = 0.0f;
        grid_bar_slow(bar, epoch);
        const float bias = bbv[col];
        for (int t = 0; t < 256; ++t) {
            float* mcur = (t & 1) ? mbuf1 : mbuf0;
            float* mnxt = (t & 1) ? mbuf0 : mbuf1;
            const float* in0 = inb + (size_t)(b0r * 256 + t) * 640;
            const float* in1 = in0 + (size_t)256 * 640;
            const float* wp = W + col;
            float a0 = 0.f, a1 = 0.f;
            #pragma unroll 4
            for (int k = 0; k < 640; k += 4) {
                float4 u0 = *(const float4*)(in0 + k);
                float4 u1 = *(const float4*)(in1 + k);
                float w0 = wp[(size_t)(k + 0) * 8192], w1 = wp[(size_t)(k + 1) * 8192];
                float w2 = wp[(size_t)(k + 2) * 8192], w3 = wp[(size_t)(k + 3) * 8192];
                a0 += w0 * u0.x + w1 * u0.y + w2 * u0.z + w3 * u0.w;
                a1 += w0 * u1.x + w1 * u1.y + w2 * u1.z + w3 * u1.w;
            }
            const float* q0 = mcur + (size_t)b0r * 640;
            const float* q1 = q0 + 640;
            #pragma unroll 4
            for (int k = 0; k < 640; k += 4) {
                float4 u0 = *(const float4*)(q0 + k);
                float4 u1 = *(const float4*)(q1 + k);
                float w0 = wp[(size_t)(640 + k + 0) * 8192], w1 = wp[(size_t)(640 + k + 1) * 8192];
                float w2 = wp[(size_t)(640 + k + 2) * 8192], w3 = wp[(size_t)(640 + k + 3) * 8192];
                a0 += w0 * u0.x + w1 * u0.y + w2 * u0.z + w3 * u0.w;
                a1 += w0 * u1.x + w1 * u1.y + w2 * u1.z + w3 * u1.w;
            }
            zbuf[c_idx * 33 + b0r + 0] = a0 + bias;
            zbuf[c_idx * 33 + b0r + 1] = a1 + bias;
            __syncthreads();
            if (tid < 256) {
                float zi = zbuf[(0 * 8 + ch) * 33 + cb];
                float zj = zbuf[(1 * 8 + ch) * 33 + cb];
                float zf = zbuf[(2 * 8 + ch) * 33 + cb];
                float zo = zbuf[(3 * 8 + ch) * 33 + cb];
                float cn = sigm(zf + 1.0f) * creg + sigm(zi) * tanhf(zj);
                creg = cn;
                hws[(size_t)(bid * 8 + ch) * 32 + cb] = sigm(zo) * tanhf(cn);
            }
            grid_bar_slow(bar, epoch);
            if (pact) {
                const int p = p_s + pj;
                const float* pp = Pr + p;
                const int k0 = kq * klen;
                float s = 0.f;
                #pragma unroll 4
                for (int k = k0; k < k0 + klen; ++k) s += hws[(size_t)k * 32 + cb] * pp[(size_t)k * 640];
                pred[(pj * 32 + cb) * kq_n + kq] = s;
            }
            __syncthreads();
            if (tid < np * 32) {
                float s = 0.f;
                for (int q2 = 0; q2 < kq_n; ++q2) s += pred[tid * kq_n + q2];
                const int p = p_s + (tid >> 5);
                const int b = tid & 31;
                mnxt[(size_t)b * 640 + p] = s;
                out[((size_t)b * 256 + t) * 640 + p] = s;
            }
            grid_bar_slow(bar, epoch);
        }
    }
}

extern "C" void kernel_launch(void* const* d_in, const int* in_sizes, int n_in,
                              void* d_out, int out_size, void* d_ws, size_t ws_size,
                              hipStream_t stream) {
    const float* x   = (const float*)d_in[0];
    const float* W0  = (const float*)d_in[1];
    const float* b0  = (const float*)d_in[2];
    const float* P0  = (const float*)d_in[3];
    const float* W1  = (const float*)d_in[4];
    const float* b1  = (const float*)d_in[5];
    const float* P1  = (const float*)d_in[6];
    float* out = (float*)d_out;

    // ws layout (bytes, 256-aligned chunks)
    size_t off = 0;
    auto alloc = [&](size_t bytes) { size_t o = off; off += (bytes + 255) & ~(size_t)255; return o; };
    const size_t oBar = alloc(4096);
    const size_t szW  = (size_t)8192 * 1280 * 2;  // Wt bf16 plane
    const size_t szQ  = (size_t)8192 * 2048 * 2;  // Qt f16
    const size_t szPt = (size_t)640 * 2048 * 2;   // Pt f16
    const size_t oWH0 = alloc(szW), oWL0 = alloc(szW), oWH1 = alloc(szW), oWL1 = alloc(szW);
    const size_t oQt0 = alloc(szQ), oQt1 = alloc(szQ);
    const size_t oPt0 = alloc(szPt), oPt1 = alloc(szPt);
    const size_t oH   = alloc((size_t)3 * HSZ * 2);
    const size_t need = off;

    hipMemsetAsync(d_ws, 0, 4096, stream);  // barrier flags start at 0 every call

    if (ws_size < need) {  // fallback path (~0.5 MB ws)
        float* ws = (float*)d_ws;
        void* args[] = {(void*)&x, (void*)&W0, (void*)&b0, (void*)&P0,
                        (void*)&W1, (void*)&b1, (void*)&P1, (void*)&out, (void*)&ws};
        hipError_t err = hipLaunchCooperativeKernel((const void*)lstm_fb,
                                                    dim3(NBLK), dim3(NTHR), args, 0, stream);
        if (err != hipSuccess)
            lstm_fb<<<dim3(NBLK), dim3(NTHR), 0, stream>>>(x, W0, b0, P0, W1, b1, P1, out, ws);
        return;
    }

    char* w = (char*)d_ws;
    u16 *WH0p = (u16*)(w + oWH0), *WL0p = (u16*)(w + oWL0);
    u16 *WH1p = (u16*)(w + oWH1), *WL1p = (u16*)(w + oWL1);
    u16 *Qt0p = (u16*)(w + oQt0), *Qt1p = (u16*)(w + oQt1);
    u16 *Pt0p = (u16*)(w + oPt0), *Pt1p = (u16*)(w + oPt1);
    u16 *hbp  = (u16*)(w + oH);
    unsigned* arrp = (unsigned*)(w + oBar);

    // precompute: weight transposes + Q = P @ Wm (all inside the graph, every call)
    transpose_split<<<dim3(256, 40), 256, 0, stream>>>(W0, WH0p, WL0p, 1280, 8192);
    transpose_split<<<dim3(256, 40), 256, 0, stream>>>(W1, WH1p, WL1p, 1280, 8192);
    transpose_f16<<<dim3(20, 64), 256, 0, stream>>>(P0, Pt0p, 2048, 640);
    transpose_f16<<<dim3(20, 64), 256, 0, stream>>>(P1, Pt1p, 2048, 640);
    qgemm<<<dim3(4096), 256, 0, stream>>>(P0, WH0p, WL0p, Qt0p);
    qgemm<<<dim3(4096), 256, 0, stream>>>(P1, WH1p, WL1p, Qt1p);

    const float *b0c = b0, *b1c = b1;
    void* args[] = {(void*)&x, (void*)&b0c, (void*)&b1c,
                    (void*)&WH0p, (void*)&WL0p, (void*)&WH1p, (void*)&WL1p,
                    (void*)&Qt0p, (void*)&Qt1p, (void*)&Pt0p, (void*)&Pt1p,
                    (void*)&hbp, (void*)&out, (void*)&arrp};
    hipError_t err = hipLaunchCooperativeKernel((const void*)lstm_q,
                                                dim3(NBLK), dim3(NTHR), args, 0, stream);
    if (err != hipSuccess)
        lstm_q<<<dim3(NBLK), dim3(NTHR), 0, stream>>>(
            x, b0c, b1c, WH0p, WL0p, WH1p, WL1p, Qt0p, Qt1p, Pt0p, Pt1p,
            hbp, out, arrp);
}